// Round 3
// baseline (1309.886 us; speedup 1.0000x reference)
//
#include <hip/hip_runtime.h>
#include <hip/hip_bf16.h>
#include <cmath>

#define LDIM 4096
#define BB 8
#define CC 512
#define GG 4
#define DD 128
#define NCHUNK 32
#define CLEN 128   // LDIM / NCHUNK

__device__ __forceinline__ float siluf(float x){ return x / (1.0f + expf(-x)); }

// ---------------- K1: LayerNorm over C; x (B,C,L) -> xn (B,C,L); zsum[b,c] += sum_l xn ----------------
__global__ __launch_bounds__(256) void k_ln1(const float* __restrict__ x,
    const float* __restrict__ lg, const float* __restrict__ lb,
    float* __restrict__ xn, float* __restrict__ zsum){
  const int b = blockIdx.y;
  const int lane = threadIdx.x & 63;
  const int wv = threadIdx.x >> 6;
  const int l = blockIdx.x*64 + lane;
  const float* xb = x + (size_t)b*CC*LDIM;
  float s=0.f, sq=0.f;
  for (int c=wv; c<CC; c+=4){
    float v = xb[(size_t)c*LDIM + l];
    s += v; sq = fmaf(v, v, sq);
  }
  __shared__ float ps[4][64], pq[4][64], smu[64], srs[64];
  ps[wv][lane]=s; pq[wv][lane]=sq;
  __syncthreads();
  if (threadIdx.x < 64){
    float t1 = ps[0][lane]+ps[1][lane]+ps[2][lane]+ps[3][lane];
    float t2 = pq[0][lane]+pq[1][lane]+pq[2][lane]+pq[3][lane];
    float mu = t1*(1.0f/CC);
    float var = t2*(1.0f/CC) - mu*mu;
    smu[lane]=mu; srs[lane]=rsqrtf(var + 1e-5f);
  }
  __syncthreads();
  const float mu = smu[lane], rs = srs[lane];
  float* xo = xn + (size_t)b*CC*LDIM;
  for (int c=wv; c<CC; c+=4){
    float v = xb[(size_t)c*LDIM + l];
    float vn = (v-mu)*rs*lg[c] + lb[c];
    xo[(size_t)c*LDIM + l] = vn;
    float r = vn;
    #pragma unroll
    for (int o=32;o;o>>=1) r += __shfl_xor(r, o, 64);
    if (lane==0) atomicAdd(&zsum[b*CC + c], r);
  }
}

// ---------------- gate MLP: gate[b,c] = sigmoid(relu(z@fc1^T+b1)@fc2^T+b2), z = zsum/L ----------------
__global__ __launch_bounds__(256) void k_gate(const float* __restrict__ zsum,
    const float* __restrict__ f1w, const float* __restrict__ f1b,
    const float* __restrict__ f2w, const float* __restrict__ f2b,
    float* __restrict__ gate){
  const int b = blockIdx.x; const int t = threadIdx.x;
  __shared__ float zs[CC]; __shared__ float hid[32];
  for (int c=t;c<CC;c+=256) zs[c] = zsum[b*CC+c] * (1.0f/LDIM);
  __syncthreads();
  if (t < 32){
    float a = f1b[t];
    for (int c=0;c<CC;c++) a = fmaf(zs[c], f1w[t*CC+c], a);
    hid[t] = a > 0.f ? a : 0.f;
  }
  __syncthreads();
  for (int c=t;c<CC;c+=256){
    float a = f2b[c];
    #pragma unroll
    for (int j=0;j<32;j++) a = fmaf(hid[j], f2w[c*32+j], a);
    gate[b*CC+c] = 1.0f/(1.0f+expf(-a));
  }
}

// ---------------- W2[g] = dt_proj_w @ xp_w[0:8] (128x128), row128 = xp_w[8] (B), row129 = xp_w[9] (C) ----------------
__global__ void k_wm(const float* __restrict__ xpw, const float* __restrict__ dtpw,
                     float* __restrict__ w2){
  const int g = blockIdx.x; const int k = threadIdx.x; // 128 threads
  const float* xw = xpw + g*10*DD;
  const float* dw = dtpw + g*DD*8;
  float* w2g = w2 + (size_t)g*132*DD;
  for (int r=0;r<DD;r++){
    float a = 0.f;
    #pragma unroll
    for (int j=0;j<8;j++) a = fmaf(dw[r*8+j], xw[j*DD+k], a);
    w2g[r*DD + k] = a;
  }
  w2g[128*DD + k] = xw[8*DD + k];
  w2g[129*DD + k] = xw[9*DD + k];
}

// ---------------- generic f32 tiled GEMM: out = A(MxK) * W(N,K)^T ----------------
// AT: A stored K-major (A[k*lda+m]); else row-major (A[m*lda+k]).
// OT: out[n*ldo+m] (transposed); else out[m*ldo+n].
// EPI: 0 none, 1 silu, 2 +bias. GN: guard n<N.
template<bool AT, bool OT, int EPI, bool GN>
__global__ __launch_bounds__(256) void k_gemm(
    const float* __restrict__ A, long long aStride, int lda,
    const float* __restrict__ W, long long wStride, int N, int K,
    float* __restrict__ O, long long oStride, int ldo,
    const float* __restrict__ bias){
  __shared__ float la[8][132], lb[8][132];
  const int t = threadIdx.x;
  const int z = blockIdx.z;
  const float* Ab = A + (size_t)z*aStride;
  const float* Wb = W + (size_t)(z & 3)*wStride;
  float* Ob = O + (size_t)z*oStride;
  const int m0 = blockIdx.x*128, n0 = blockIdx.y*128;
  const int tx = t & 15, ty = t >> 4;
  float acc[8][8];
  #pragma unroll
  for (int i=0;i<8;i++)
    #pragma unroll
    for (int j=0;j<8;j++) acc[i][j]=0.f;

  for (int k0=0;k0<K;k0+=8){
    if constexpr (AT){
      const int kk = t >> 5, mm = (t & 31) << 2;
      float4 v = *(const float4*)&Ab[(size_t)(k0+kk)*lda + m0 + mm];
      *(float4*)&la[kk][mm] = v;
    } else {
      const int mm = t >> 1, kh = (t & 1) << 2;
      float4 v = *(const float4*)&Ab[(size_t)(m0+mm)*lda + k0 + kh];
      la[kh+0][mm]=v.x; la[kh+1][mm]=v.y; la[kh+2][mm]=v.z; la[kh+3][mm]=v.w;
    }
    {
      const int nn = t >> 1, kh = (t & 1) << 2;
      float4 v = make_float4(0.f,0.f,0.f,0.f);
      if (!GN || (n0+nn) < N) v = *(const float4*)&Wb[(size_t)(n0+nn)*K + k0 + kh];
      lb[kh+0][nn]=v.x; lb[kh+1][nn]=v.y; lb[kh+2][nn]=v.z; lb[kh+3][nn]=v.w;
    }
    __syncthreads();
    #pragma unroll
    for (int k=0;k<8;k++){
      float4 a0 = *(const float4*)&la[k][tx<<2];
      float4 a1 = *(const float4*)&la[k][(tx<<2)+64];
      float4 b0 = *(const float4*)&lb[k][ty<<2];
      float4 b1 = *(const float4*)&lb[k][(ty<<2)+64];
      float av[8] = {a0.x,a0.y,a0.z,a0.w,a1.x,a1.y,a1.z,a1.w};
      float bv[8] = {b0.x,b0.y,b0.z,b0.w,b1.x,b1.y,b1.z,b1.w};
      #pragma unroll
      for (int i=0;i<8;i++){
        #pragma unroll
        for (int j=0;j<8;j++) acc[i][j] = fmaf(av[i], bv[j], acc[i][j]);
      }
    }
    __syncthreads();
  }

  if constexpr (OT){
    #pragma unroll
    for (int j=0;j<8;j++){
      const int n = n0 + (ty<<2) + ((j>>2)<<6) + (j&3);
      if (GN && n >= N) continue;
      float bvv = (EPI==2) ? bias[n] : 0.f;
      #pragma unroll
      for (int ih=0;ih<2;ih++){
        const int m = m0 + (tx<<2) + (ih<<6);
        float4 v = make_float4(acc[ih*4+0][j],acc[ih*4+1][j],acc[ih*4+2][j],acc[ih*4+3][j]);
        if (EPI==1){ v.x=siluf(v.x); v.y=siluf(v.y); v.z=siluf(v.z); v.w=siluf(v.w); }
        if (EPI==2){ v.x+=bvv; v.y+=bvv; v.z+=bvv; v.w+=bvv; }
        *(float4*)&Ob[(size_t)n*ldo + m] = v;
      }
    }
  } else {
    #pragma unroll
    for (int i=0;i<8;i++){
      const int m = m0 + (tx<<2) + ((i>>2)<<6) + (i&3);
      #pragma unroll
      for (int jh=0;jh<2;jh++){
        const int nb = n0 + (ty<<2) + (jh<<6);
        if (!GN){
          float4 v = make_float4(acc[i][jh*4+0],acc[i][jh*4+1],acc[i][jh*4+2],acc[i][jh*4+3]);
          if (EPI==1){ v.x=siluf(v.x); v.y=siluf(v.y); v.z=siluf(v.z); v.w=siluf(v.w); }
          *(float4*)&Ob[(size_t)m*ldo + nb] = v;
        } else {
          #pragma unroll
          for (int jj=0;jj<4;jj++){
            const int n = nb + jj;
            if (n < N) Ob[(size_t)m*ldo + n] = acc[i][jh*4+jj];
          }
        }
      }
    }
  }
}

// ---------------- depthwise 3x3 conv + bias + silu; xd (B*G,L,D) -> u (B*G,L,D) ----------------
__global__ __launch_bounds__(256) void k_conv(const float* __restrict__ xd,
    const float* __restrict__ cw, const float* __restrict__ cb, float* __restrict__ u){
  const int z = blockIdx.y; const int g = z & 3;
  const int d = threadIdx.x & 127;
  const int li = threadIdx.x >> 7;
  const int l0 = blockIdx.x * 32;
  float w[9];
  #pragma unroll
  for (int q=0;q<9;q++) w[q] = cw[(g*DD + d)*9 + q];
  const float bsv = cb[g*DD + d];
  const float* xb = xd + (size_t)z*LDIM*DD;
  float* ubp = u + (size_t)z*LDIM*DD;
  for (int ll=li; ll<32; ll+=2){
    const int l = l0 + ll;
    const int h = l >> 6, wc = l & 63;
    float a = bsv;
    #pragma unroll
    for (int ky=0;ky<3;ky++){
      const int hh = h + ky - 1;
      if (hh < 0 || hh >= 64) continue;
      #pragma unroll
      for (int kx=0;kx<3;kx++){
        const int wq = wc + kx - 1;
        if (wq < 0 || wq >= 64) continue;
        a = fmaf(xb[(size_t)(hh*64+wq)*DD + d], w[ky*3+kx], a);
      }
    }
    ubp[(size_t)l*DD + d] = siluf(a);
  }
}

// scan-space -> memory-space index map (g0 = group index 0..3 <-> modes 1..4)
__device__ __forceinline__ int scan_lmem(int g0, int ls){
  int j = (g0 >= 2) ? (LDIM-1-ls) : ls;
  return (g0 & 1) ? (((j & 63)<<6) + (j >> 6)) : j;
}

// ---------------- scan phase A: per chunk local (P = prod dA, q = local h) ----------------
__global__ __launch_bounds__(128) void k_scanA(const float* __restrict__ pd,
    const float* __restrict__ u, const float* __restrict__ dtb,
    const float* __restrict__ alog, float* __restrict__ P, float* __restrict__ Q){
  const int z = blockIdx.y; const int g = z & 3; const int ch = blockIdx.x;
  const int d = threadIdx.x;
  const float bv = dtb[g*DD + d];
  const float Ad = -expf(alog[g*DD + d]);
  const float* pdb = pd + (size_t)z*LDIM*132;
  const float* ubp = u + (size_t)z*LDIM*DD;
  float Pp = 1.f, q = 0.f;
  for (int i=0;i<CLEN;i++){
    const int lm = scan_lmem(g, ch*CLEN + i);
    const float* row = pdb + (size_t)lm*132;
    float pre = row[d];
    float Bm  = row[128];
    float uv  = ubp[(size_t)lm*DD + d];
    float xa = pre + bv;
    float delta = (xa > 20.f) ? xa : log1pf(expf(xa));
    float dA = expf(Ad * delta);
    Pp *= dA;
    q = fmaf(dA, q, delta * uv * Bm);
  }
  const int idx = (z*NCHUNK + ch)*DD + d;
  P[idx] = Pp; Q[idx] = q;
}

// ---------------- scan phase B: combine chunks ----------------
__global__ __launch_bounds__(128) void k_scanB(const float* __restrict__ P,
    const float* __restrict__ Q, float* __restrict__ hin){
  const int z = blockIdx.x; const int d = threadIdx.x;
  float h = 0.f;
  for (int j=0;j<NCHUNK;j++){
    const int idx = (z*NCHUNK + j)*DD + d;
    hin[idx] = h;
    h = fmaf(P[idx], h, Q[idx]);
  }
}

// ---------------- scan phase C: rescan, y = h*C + Ds*u written in-place into pd rows ----------------
__global__ __launch_bounds__(128) void k_scanC(float* __restrict__ pd,
    const float* __restrict__ u, const float* __restrict__ dtb,
    const float* __restrict__ alog, const float* __restrict__ dsp,
    const float* __restrict__ hin){
  const int z = blockIdx.y; const int g = z & 3; const int ch = blockIdx.x;
  const int d = threadIdx.x;
  const float bv = dtb[g*DD + d];
  const float Ad = -expf(alog[g*DD + d]);
  const float Dv = dsp[g*DD + d];
  float* pdb = pd + (size_t)z*LDIM*132;
  const float* ubp = u + (size_t)z*LDIM*DD;
  float h = hin[(z*NCHUNK + ch)*DD + d];
  for (int i=0;i<CLEN;i++){
    const int lm = scan_lmem(g, ch*CLEN + i);
    float* row = pdb + (size_t)lm*132;
    float pre = row[d];
    float Bm  = row[128];
    float Cm  = row[129];
    float uv  = ubp[(size_t)lm*DD + d];
    float xa = pre + bv;
    float delta = (xa > 20.f) ? xa : log1pf(expf(xa));
    float dA = expf(Ad * delta);
    h = fmaf(dA, h, delta * uv * Bm);
    row[d] = fmaf(h, Cm, Dv * uv);
  }
}

// ---------------- LN over D=128 per row (stride 132) * zsilu -> ynz (stride 128) ----------------
__global__ __launch_bounds__(256) void k_yln(const float* __restrict__ y,
    const float* __restrict__ zs, const float* __restrict__ og,
    const float* __restrict__ ob, float* __restrict__ ynz){
  const int row = blockIdx.x*4 + (threadIdx.x >> 6);
  const int lane = threadIdx.x & 63;
  const int g = (row >> 12) & 3;
  const float* r = y + (size_t)row*132;
  float v0 = r[lane], v1 = r[lane+64];
  float s = v0+v1, sq = fmaf(v0,v0, v1*v1);
  #pragma unroll
  for (int o=32;o;o>>=1){ s += __shfl_xor(s,o,64); sq += __shfl_xor(sq,o,64); }
  const float mu = s*(1.0f/DD);
  const float var = sq*(1.0f/DD) - mu*mu;
  const float rs = rsqrtf(var + 1e-5f);
  const size_t base = (size_t)row*DD;
  float o0 = (v0-mu)*rs*og[g*DD+lane]    + ob[g*DD+lane];
  float o1 = (v1-mu)*rs*og[g*DD+lane+64] + ob[g*DD+lane+64];
  ynz[base+lane]    = o0 * zs[base+lane];
  ynz[base+lane+64] = o1 * zs[base+lane+64];
}

// ---------------- final merge: xm = ygrp*skip*xn*gate, LN over C, in-place ----------------
__global__ __launch_bounds__(256) void k_ln2(float* __restrict__ yg,
    const float* __restrict__ xn, const float* __restrict__ gate,
    const float* __restrict__ lg, const float* __restrict__ lb,
    const float* __restrict__ skp){
  const int b = blockIdx.y;
  const int lane = threadIdx.x & 63;
  const int wv = threadIdx.x >> 6;
  const int l = blockIdx.x*64 + lane;
  const float sk = skp[0];
  const float* xb = xn + (size_t)b*CC*LDIM;
  float* yb = yg + (size_t)b*CC*LDIM;
  const float* gb = gate + b*CC;
  float s=0.f, sq=0.f;
  for (int c=wv;c<CC;c+=4){
    float v = yb[(size_t)c*LDIM+l] * sk * xb[(size_t)c*LDIM+l] * gb[c];
    s += v; sq = fmaf(v,v,sq);
  }
  __shared__ float ps[4][64], pq[4][64], smu[64], srs[64];
  ps[wv][lane]=s; pq[wv][lane]=sq;
  __syncthreads();
  if (threadIdx.x < 64){
    float t1 = ps[0][lane]+ps[1][lane]+ps[2][lane]+ps[3][lane];
    float t2 = pq[0][lane]+pq[1][lane]+pq[2][lane]+pq[3][lane];
    float mu = t1*(1.0f/CC);
    float var = t2*(1.0f/CC) - mu*mu;
    smu[lane]=mu; srs[lane]=rsqrtf(var + 1e-5f);
  }
  __syncthreads();
  const float mu = smu[lane], rs = srs[lane];
  for (int c=wv;c<CC;c+=4){
    float v = yb[(size_t)c*LDIM+l] * sk * xb[(size_t)c*LDIM+l] * gb[c];
    yb[(size_t)c*LDIM+l] = (v-mu)*rs*lg[c] + lb[c];
  }
}

extern "C" void kernel_launch(void* const* d_in, const int* in_sizes, int n_in,
                              void* d_out, int out_size, void* d_ws, size_t ws_size,
                              hipStream_t stream) {
  const float* x    = (const float*)d_in[0];
  const float* ln_g = (const float*)d_in[1];
  const float* ln_b = (const float*)d_in[2];
  const float* f1w  = (const float*)d_in[3];
  const float* f1b  = (const float*)d_in[4];
  const float* f2w  = (const float*)d_in[5];
  const float* f2b  = (const float*)d_in[6];
  const float* ipw  = (const float*)d_in[7];
  const float* cw   = (const float*)d_in[8];
  const float* cb   = (const float*)d_in[9];
  const float* xpw  = (const float*)d_in[10];
  const float* dtpw = (const float*)d_in[11];
  const float* dtpb = (const float*)d_in[12];
  const float* alog = (const float*)d_in[13];
  const float* dsp  = (const float*)d_in[14];
  const float* ong  = (const float*)d_in[15];
  const float* onb  = (const float*)d_in[16];
  const float* opw  = (const float*)d_in[17];
  const float* pjw  = (const float*)d_in[18];
  const float* pjb  = (const float*)d_in[19];
  const float* skp  = (const float*)d_in[20];

  float* ws   = (float*)d_ws;
  float* xn   = ws;                       // 16,777,216  (B,C,L)
  float* ub   = ws + 16777216;            // 16,777,216  (B*G,L,128) u / later ynz
  float* pd   = ws + 33554432;            // 17,301,504  (B*G,L,132) pre-delta/B/C -> y -> ygrp(B,C,L) -> xmn
  float* zsum = ws + 50855936;            // 4096
  float* gate = ws + 50860032;            // 4096
  float* w2   = ws + 50864128;            // 4*132*128
  float* Pb   = ws + 50931712;            // 131072
  float* Qb   = ws + 51062784;            // 131072
  float* hin  = ws + 51193856;            // 131072
  float* xdz  = (float*)d_out;            // xd, then zsilu scratch (exactly out_size floats)

  hipMemsetAsync(zsum, 0, 4096*sizeof(float), stream);

  k_ln1<<<dim3(64, BB), 256, 0, stream>>>(x, ln_g, ln_b, xn, zsum);
  k_gate<<<BB, 256, 0, stream>>>(zsum, f1w, f1b, f2w, f2b, gate);
  k_wm<<<GG, 128, 0, stream>>>(xpw, dtpw, w2);

  // G1a: xd = xn_chunk @ in_proj_w[g][0:128]^T  -> xdz (B*G,L,128)
  k_gemm<true,false,0,false><<<dim3(32,1,32), 256, 0, stream>>>(
      xn, 128LL*LDIM, LDIM, ipw, 256LL*128, 128, 128, xdz, 128LL*LDIM, 128, nullptr);

  // depthwise conv + silu -> u
  k_conv<<<dim3(128,32), 256, 0, stream>>>(xdz, cw, cb, ub);

  // G2: pd = u @ W2^T (N=130: pre-delta, B, C), row stride 132
  k_gemm<false,false,0,true><<<dim3(32,2,32), 256, 0, stream>>>(
      ub, 128LL*LDIM, 128, w2, 132LL*128, 130, 128, pd, 132LL*LDIM, 132, nullptr);

  // chunked selective scan
  k_scanA<<<dim3(NCHUNK,32), 128, 0, stream>>>(pd, ub, dtpb, alog, Pb, Qb);
  k_scanB<<<32, 128, 0, stream>>>(Pb, Qb, hin);
  k_scanC<<<dim3(NCHUNK,32), 128, 0, stream>>>(pd, ub, dtpb, alog, dsp, hin);

  // G1b: zsilu = silu(xn_chunk @ in_proj_w[g][128:256]^T) -> xdz
  k_gemm<true,false,1,false><<<dim3(32,1,32), 256, 0, stream>>>(
      xn, 128LL*LDIM, LDIM, ipw + 128*128, 256LL*128, 128, 128, xdz, 128LL*LDIM, 128, nullptr);

  // LN over D * zsilu -> ynz (into ub)
  k_yln<<<32768, 256, 0, stream>>>(pd, xdz, ong, onb, ub);

  // G3: ygrp = ynz @ out_proj_w[g]^T, written transposed into pd as (B,C,L)
  k_gemm<false,true,0,false><<<dim3(32,1,32), 256, 0, stream>>>(
      ub, 128LL*LDIM, 128, opw, 128LL*128, 128, 128, pd, 128LL*LDIM, LDIM, nullptr);

  // final merge + LN over C (in-place in pd as (B,C,L))
  k_ln2<<<dim3(64, BB), 256, 0, stream>>>(pd, xn, gate, ln_g, ln_b, skp);

  // G4: out = xmn @ proj_w^T + proj_b, written transposed to d_out (B,C,L)
  k_gemm<true,true,2,false><<<dim3(32,4,BB), 256, 0, stream>>>(
      pd, 512LL*LDIM, LDIM, pjw, 0LL, 512, 512, (float*)d_out, 512LL*LDIM, LDIM, pjb);

  (void)in_sizes; (void)n_in; (void)out_size; (void)ws_size;
}

// Round 5
// 923.312 us; speedup vs baseline: 1.4187x; 1.4187x over previous
//
#include <hip/hip_runtime.h>
#include <hip/hip_bf16.h>
#include <cmath>

#define LDIM 4096
#define BB 8
#define CC 512
#define GG 4
#define DD 128
#define NCHUNK 32
#define CLEN 128   // LDIM / NCHUNK

typedef __attribute__((ext_vector_type(4))) float f32x4;
typedef __attribute__((ext_vector_type(8))) short short8;
typedef __attribute__((ext_vector_type(4))) short s16x4;

__device__ __forceinline__ float siluf(float x){ return x / (1.0f + expf(-x)); }

// f32 -> bf16 bits, round-to-nearest-even
__device__ __forceinline__ short f2bf(float f){
  union { float f; unsigned u; } v; v.f = f;
  unsigned r = v.u + 0x7FFFu + ((v.u >> 16) & 1u);
  return (short)(r >> 16);
}

// ---------------- K1: LayerNorm over C; x (B,C,L) -> xncm (B,C,L); zsum[b,c] += sum_l xn ----------------
__global__ __launch_bounds__(256) void k_ln1(const float* __restrict__ x,
    const float* __restrict__ lg, const float* __restrict__ lb,
    float* __restrict__ xn, float* __restrict__ zsum){
  const int b = blockIdx.y;
  const int lane = threadIdx.x & 63;
  const int wv = threadIdx.x >> 6;
  const int l = blockIdx.x*64 + lane;
  const float* xb = x + (size_t)b*CC*LDIM;
  float s=0.f, sq=0.f;
  for (int c=wv; c<CC; c+=4){
    float v = xb[(size_t)c*LDIM + l];
    s += v; sq = fmaf(v, v, sq);
  }
  __shared__ float ps[4][64], pq[4][64], smu[64], srs[64];
  ps[wv][lane]=s; pq[wv][lane]=sq;
  __syncthreads();
  if (threadIdx.x < 64){
    float t1 = ps[0][lane]+ps[1][lane]+ps[2][lane]+ps[3][lane];
    float t2 = pq[0][lane]+pq[1][lane]+pq[2][lane]+pq[3][lane];
    float mu = t1*(1.0f/CC);
    float var = t2*(1.0f/CC) - mu*mu;
    smu[lane]=mu; srs[lane]=rsqrtf(var + 1e-5f);
  }
  __syncthreads();
  const float mu = smu[lane], rs = srs[lane];
  float* xo = xn + (size_t)b*CC*LDIM;
  for (int c=wv; c<CC; c+=4){
    float v = xb[(size_t)c*LDIM + l];
    float vn = (v-mu)*rs*lg[c] + lb[c];
    xo[(size_t)c*LDIM + l] = vn;
    float r = vn;
    #pragma unroll
    for (int o=32;o;o>>=1) r += __shfl_xor(r, o, 64);
    if (lane==0) atomicAdd(&zsum[b*CC + c], r);
  }
}

// ---------------- transpose (B,C,L) -> (B,L,C) ----------------
__global__ __launch_bounds__(256) void k_tr(const float* __restrict__ in, float* __restrict__ out){
  __shared__ float tile[64][65];
  const int l0 = blockIdx.x*64, c0 = blockIdx.y*64, b = blockIdx.z;
  const int lane = threadIdx.x & 63, rr = threadIdx.x >> 6;
  const float* ib = in + (size_t)b*CC*LDIM;
  float* ob = out + (size_t)b*LDIM*CC;
  for (int i = rr; i < 64; i += 4)
    tile[i][lane] = ib[(size_t)(c0+i)*LDIM + l0 + lane];
  __syncthreads();
  for (int i = rr; i < 64; i += 4)
    ob[(size_t)(l0+i)*CC + c0 + lane] = tile[lane][i];
}

// ---------------- gate MLP ----------------
__global__ __launch_bounds__(256) void k_gate(const float* __restrict__ zsum,
    const float* __restrict__ f1w, const float* __restrict__ f1b,
    const float* __restrict__ f2w, const float* __restrict__ f2b,
    float* __restrict__ gate){
  const int b = blockIdx.x; const int t = threadIdx.x;
  __shared__ float zs[CC]; __shared__ float hid[32];
  for (int c=t;c<CC;c+=256) zs[c] = zsum[b*CC+c] * (1.0f/LDIM);
  __syncthreads();
  if (t < 32){
    float a = f1b[t];
    for (int c=0;c<CC;c++) a = fmaf(zs[c], f1w[t*CC+c], a);
    hid[t] = a > 0.f ? a : 0.f;
  }
  __syncthreads();
  for (int c=t;c<CC;c+=256){
    float a = f2b[c];
    #pragma unroll
    for (int j=0;j<32;j++) a = fmaf(hid[j], f2w[c*32+j], a);
    gate[b*CC+c] = 1.0f/(1.0f+expf(-a));
  }
}

// ---------------- W2[g] = dt_proj_w @ xp_w[0:8] (128x128), row128 = B-row, row129 = C-row ----------------
__global__ void k_wm(const float* __restrict__ xpw, const float* __restrict__ dtpw,
                     float* __restrict__ w2){
  const int g = blockIdx.x; const int k = threadIdx.x; // 128 threads
  const float* xw = xpw + g*10*DD;
  const float* dw = dtpw + g*DD*8;
  float* w2g = w2 + (size_t)g*132*DD;
  for (int r=0;r<DD;r++){
    float a = 0.f;
    #pragma unroll
    for (int j=0;j<8;j++) a = fmaf(dw[r*8+j], xw[j*DD+k], a);
    w2g[r*DD + k] = a;
  }
  w2g[128*DD + k] = xw[8*DD + k];
  w2g[129*DD + k] = xw[9*DD + k];
}

// ---------------- bf16 MFMA GEMM: out(M x N) = A(M,K) * B(N,K)^T, all row-major k-contig f32 in global ----
// block: 128 x (NF*32), 256 thr = 4 waves (2x2), wave tile 64 x (NF*16). BK=32.
// batch z: Ab = A + (z>>2)*aHi + (z&3)*aLo ; Wb likewise ; Ob likewise.
// EPI: 0 none, 1 silu, 2 +bias[m]. GN: guard col<Nlim (B rows >=Nlim read as 0).
template<int NF, int EPI, bool GN>
__global__ __launch_bounds__(256) void k_mfma(
    const float* __restrict__ A, long long aHi, long long aLo, int lda,
    const float* __restrict__ Bw, long long bHi, long long bLo,
    float* __restrict__ O, long long oHi, long long oLo, int ldo,
    int K, int Nlim, const float* __restrict__ bias){
  constexpr int BN = NF*32;
  constexpr int SPAN = NF*16;
  __shared__ __align__(16) short la[128*32];
  __shared__ __align__(16) short lb[BN*32];
  const int t = threadIdx.x;
  const int z = blockIdx.z;
  const float* Ab = A + (size_t)(z>>2)*aHi + (size_t)(z&3)*aLo + (size_t)blockIdx.x*128*lda;
  const float* Wb = Bw + (size_t)(z>>2)*bHi + (size_t)(z&3)*bLo + (size_t)blockIdx.y*BN*K;
  float* Ob = O + (size_t)(z>>2)*oHi + (size_t)(z&3)*oLo;
  const int m0 = blockIdx.x*128, n0 = blockIdx.y*BN;
  const int l = t & 63, w = t >> 6;
  const int wr = w >> 1, wc = w & 1;
  f32x4 acc[4][NF];
  #pragma unroll
  for (int i=0;i<4;i++)
    #pragma unroll
    for (int j=0;j<NF;j++) acc[i][j] = (f32x4){0.f,0.f,0.f,0.f};

  for (int k0 = 0; k0 < K; k0 += 32){
    #pragma unroll
    for (int i=0;i<4;i++){           // A tile: 128 rows x 32k
      const int idx = t + 256*i;
      const int r = idx >> 3, kq = idx & 7;
      float4 v = *(const float4*)&Ab[(size_t)r*lda + k0 + kq*4];
      const int e = r*32 + ((((kq>>1) ^ ((r>>1)&3)))<<3) + ((kq&1)<<2);
      *(s16x4*)&la[e] = (s16x4){f2bf(v.x), f2bf(v.y), f2bf(v.z), f2bf(v.w)};
    }
    #pragma unroll
    for (int i=0;i<NF;i++){          // B tile: BN rows x 32k
      const int idx = t + 256*i;
      const int r = idx >> 3, kq = idx & 7;
      float4 v = make_float4(0.f,0.f,0.f,0.f);
      if (!GN || r < Nlim) v = *(const float4*)&Wb[(size_t)r*K + k0 + kq*4];
      const int e = r*32 + ((((kq>>1) ^ ((r>>1)&3)))<<3) + ((kq&1)<<2);
      *(s16x4*)&lb[e] = (s16x4){f2bf(v.x), f2bf(v.y), f2bf(v.z), f2bf(v.w)};
    }
    __syncthreads();
    short8 af[4], bf[NF];
    #pragma unroll
    for (int mf=0; mf<4; mf++){
      const int R = wr*64 + mf*16 + (l&15);
      const int q = (l>>4) ^ ((R>>1)&3);
      af[mf] = *(const short8*)&la[R*32 + q*8];
    }
    #pragma unroll
    for (int nf=0; nf<NF; nf++){
      const int R = wc*SPAN + nf*16 + (l&15);
      const int q = (l>>4) ^ ((R>>1)&3);
      bf[nf] = *(const short8*)&lb[R*32 + q*8];
    }
    #pragma unroll
    for (int mf=0; mf<4; mf++)
      #pragma unroll
      for (int nf=0; nf<NF; nf++)
        acc[mf][nf] = __builtin_amdgcn_mfma_f32_16x16x32_bf16(af[mf], bf[nf], acc[mf][nf], 0, 0, 0);
    __syncthreads();
  }

  #pragma unroll
  for (int mf=0; mf<4; mf++){
    #pragma unroll
    for (int j=0;j<4;j++){
      const int m = m0 + wr*64 + mf*16 + ((l>>4)<<2) + j;
      const float bv = (EPI==2) ? bias[m] : 0.f;
      #pragma unroll
      for (int nf=0; nf<NF; nf++){
        const int n = n0 + wc*SPAN + nf*16 + (l&15);
        if (GN && n >= Nlim) continue;
        float v = acc[mf][nf][j];
        if (EPI==1) v = siluf(v);
        if (EPI==2) v += bv;
        Ob[(size_t)m*ldo + n] = v;
      }
    }
  }
}

// ---------------- depthwise 3x3 conv + bias + silu; xd (B*G,L,D) -> u (B*G,L,D) ----------------
__global__ __launch_bounds__(256) void k_conv(const float* __restrict__ xd,
    const float* __restrict__ cw, const float* __restrict__ cb, float* __restrict__ u){
  const int z = blockIdx.y; const int g = z & 3;
  const int d = threadIdx.x & 127;
  const int li = threadIdx.x >> 7;
  const int l0 = blockIdx.x * 32;
  float w[9];
  #pragma unroll
  for (int q=0;q<9;q++) w[q] = cw[(g*DD + d)*9 + q];
  const float bsv = cb[g*DD + d];
  const float* xb = xd + (size_t)z*LDIM*DD;
  float* ubp = u + (size_t)z*LDIM*DD;
  for (int ll=li; ll<32; ll+=2){
    const int l = l0 + ll;
    const int h = l >> 6, wc = l & 63;
    float a = bsv;
    #pragma unroll
    for (int ky=0;ky<3;ky++){
      const int hh = h + ky - 1;
      if (hh < 0 || hh >= 64) continue;
      #pragma unroll
      for (int kx=0;kx<3;kx++){
        const int wq = wc + kx - 1;
        if (wq < 0 || wq >= 64) continue;
        a = fmaf(xb[(size_t)(hh*64+wq)*DD + d], w[ky*3+kx], a);
      }
    }
    ubp[(size_t)l*DD + d] = siluf(a);
  }
}

// scan-space -> memory-space index map
__device__ __forceinline__ int scan_lmem(int g0, int ls){
  int j = (g0 >= 2) ? (LDIM-1-ls) : ls;
  return (g0 & 1) ? (((j & 63)<<6) + (j >> 6)) : j;
}

// ---------------- scan phase A ----------------
__global__ __launch_bounds__(128) void k_scanA(const float* __restrict__ pd,
    const float* __restrict__ u, const float* __restrict__ dtb,
    const float* __restrict__ alog, float* __restrict__ P, float* __restrict__ Q){
  const int z = blockIdx.y; const int g = z & 3; const int ch = blockIdx.x;
  const int d = threadIdx.x;
  const float bv = dtb[g*DD + d];
  const float Ad = -expf(alog[g*DD + d]);
  const float* pdb = pd + (size_t)z*LDIM*132;
  const float* ubp = u + (size_t)z*LDIM*DD;
  float Pp = 1.f, q = 0.f;
  for (int i=0;i<CLEN;i++){
    const int lm = scan_lmem(g, ch*CLEN + i);
    const float* row = pdb + (size_t)lm*132;
    float pre = row[d];
    float Bm  = row[128];
    float uv  = ubp[(size_t)lm*DD + d];
    float xa = pre + bv;
    float delta = (xa > 20.f) ? xa : log1pf(expf(xa));
    float dA = expf(Ad * delta);
    Pp *= dA;
    q = fmaf(dA, q, delta * uv * Bm);
  }
  const int idx = (z*NCHUNK + ch)*DD + d;
  P[idx] = Pp; Q[idx] = q;
}

// ---------------- scan phase B ----------------
__global__ __launch_bounds__(128) void k_scanB(const float* __restrict__ P,
    const float* __restrict__ Q, float* __restrict__ hin){
  const int z = blockIdx.x; const int d = threadIdx.x;
  float h = 0.f;
  for (int j=0;j<NCHUNK;j++){
    const int idx = (z*NCHUNK + j)*DD + d;
    hin[idx] = h;
    h = fmaf(P[idx], h, Q[idx]);
  }
}

// ---------------- scan phase C ----------------
__global__ __launch_bounds__(128) void k_scanC(float* __restrict__ pd,
    const float* __restrict__ u, const float* __restrict__ dtb,
    const float* __restrict__ alog, const float* __restrict__ dsp,
    const float* __restrict__ hin){
  const int z = blockIdx.y; const int g = z & 3; const int ch = blockIdx.x;
  const int d = threadIdx.x;
  const float bv = dtb[g*DD + d];
  const float Ad = -expf(alog[g*DD + d]);
  const float Dv = dsp[g*DD + d];
  float* pdb = pd + (size_t)z*LDIM*132;
  const float* ubp = u + (size_t)z*LDIM*DD;
  float h = hin[(z*NCHUNK + ch)*DD + d];
  for (int i=0;i<CLEN;i++){
    const int lm = scan_lmem(g, ch*CLEN + i);
    float* row = pdb + (size_t)lm*132;
    float pre = row[d];
    float Bm  = row[128];
    float Cm  = row[129];
    float uv  = ubp[(size_t)lm*DD + d];
    float xa = pre + bv;
    float delta = (xa > 20.f) ? xa : log1pf(expf(xa));
    float dA = expf(Ad * delta);
    h = fmaf(dA, h, delta * uv * Bm);
    row[d] = fmaf(h, Cm, Dv * uv);
  }
}

// ---------------- LN over D=128 per row (stride 132) * zsilu -> ynz (stride 128) ----------------
__global__ __launch_bounds__(256) void k_yln(const float* __restrict__ y,
    const float* __restrict__ zs, const float* __restrict__ og,
    const float* __restrict__ ob, float* __restrict__ ynz){
  const int row = blockIdx.x*4 + (threadIdx.x >> 6);
  const int lane = threadIdx.x & 63;
  const int g = (row >> 12) & 3;
  const float* r = y + (size_t)row*132;
  float v0 = r[lane], v1 = r[lane+64];
  float s = v0+v1, sq = fmaf(v0,v0, v1*v1);
  #pragma unroll
  for (int o=32;o;o>>=1){ s += __shfl_xor(s,o,64); sq += __shfl_xor(sq,o,64); }
  const float mu = s*(1.0f/DD);
  const float var = sq*(1.0f/DD) - mu*mu;
  const float rs = rsqrtf(var + 1e-5f);
  const size_t base = (size_t)row*DD;
  float o0 = (v0-mu)*rs*og[g*DD+lane]    + ob[g*DD+lane];
  float o1 = (v1-mu)*rs*og[g*DD+lane+64] + ob[g*DD+lane+64];
  ynz[base+lane]    = o0 * zs[base+lane];
  ynz[base+lane+64] = o1 * zs[base+lane+64];
}

// ---------------- final merge on (B,L,C): xm = ygrp*skip*xn*gate, LN over C, in-place. 1 wave/row ----
__global__ __launch_bounds__(256) void k_ln2r(float* __restrict__ yg,
    const float* __restrict__ xnT, const float* __restrict__ gate,
    const float* __restrict__ lg, const float* __restrict__ lb,
    const float* __restrict__ skp){
  const int row = blockIdx.x*4 + (threadIdx.x >> 6);   // (b,l) row, 0..32767
  const int b = row >> 12;
  const int lane = threadIdx.x & 63;
  const float sk = skp[0];
  float* yr = yg + (size_t)row*CC;
  const float* xr = xnT + (size_t)row*CC;
  const float* gb = gate + b*CC;
  float v[8]; float s=0.f, sq=0.f;
  #pragma unroll
  for (int i=0;i<8;i++){
    const int c = lane + 64*i;
    float val = yr[c] * sk * xr[c] * gb[c];
    v[i] = val; s += val; sq = fmaf(val,val,sq);
  }
  #pragma unroll
  for (int o=32;o;o>>=1){ s += __shfl_xor(s,o,64); sq += __shfl_xor(sq,o,64); }
  const float mu = s*(1.0f/CC);
  const float var = sq*(1.0f/CC) - mu*mu;
  const float rs = rsqrtf(var + 1e-5f);
  #pragma unroll
  for (int i=0;i<8;i++){
    const int c = lane + 64*i;
    yr[c] = (v[i]-mu)*rs*lg[c] + lb[c];
  }
}

extern "C" void kernel_launch(void* const* d_in, const int* in_sizes, int n_in,
                              void* d_out, int out_size, void* d_ws, size_t ws_size,
                              hipStream_t stream) {
  const float* x    = (const float*)d_in[0];
  const float* ln_g = (const float*)d_in[1];
  const float* ln_b = (const float*)d_in[2];
  const float* f1w  = (const float*)d_in[3];
  const float* f1b  = (const float*)d_in[4];
  const float* f2w  = (const float*)d_in[5];
  const float* f2b  = (const float*)d_in[6];
  const float* ipw  = (const float*)d_in[7];
  const float* cw   = (const float*)d_in[8];
  const float* cb   = (const float*)d_in[9];
  const float* xpw  = (const float*)d_in[10];
  const float* dtpw = (const float*)d_in[11];
  const float* dtpb = (const float*)d_in[12];
  const float* alog = (const float*)d_in[13];
  const float* dsp  = (const float*)d_in[14];
  const float* ong  = (const float*)d_in[15];
  const float* onb  = (const float*)d_in[16];
  const float* opw  = (const float*)d_in[17];
  const float* pjw  = (const float*)d_in[18];
  const float* pjb  = (const float*)d_in[19];
  const float* skp  = (const float*)d_in[20];

  float* ws   = (float*)d_ws;
  float* xn   = ws;                       // (B,L,C) row-major LN output
  float* ub   = ws + 16777216;            // (B*G,L,128) u / later ynz
  float* pd   = ws + 33554432;            // scratch: xn_cm -> (B*G,L,132) pd/y -> (B,L,C) ygrp/xmn
  float* zsum = ws + 50855936;            // 4096
  float* gate = ws + 50860032;            // 4096
  float* w2   = ws + 50864128;            // 4*132*128
  float* Pb   = ws + 50931712;            // 131072
  float* Qb   = ws + 51062784;            // 131072
  float* hin  = ws + 51193856;            // 131072
  float* xdz  = (float*)d_out;            // xd, then zsilu scratch

  const long long LC  = (long long)LDIM*CC;     // 2M
  const long long LD  = (long long)LDIM*DD;     // 512K
  const long long LPD = (long long)LDIM*132;

  hipMemsetAsync(zsum, 0, 4096*sizeof(float), stream);

  k_ln1<<<dim3(64, BB), 256, 0, stream>>>(x, ln_g, ln_b, pd, zsum);
  k_gate<<<BB, 256, 0, stream>>>(zsum, f1w, f1b, f2w, f2b, gate);
  k_wm<<<GG, 128, 0, stream>>>(xpw, dtpw, w2);
  k_tr<<<dim3(64, 8, BB), 256, 0, stream>>>(pd, xn);

  // G1a: xd[z][l][d] = xn[b][l][g*128+k] @ ipw[g][0:128]
  k_mfma<4,0,false><<<dim3(32,1,32), 256, 0, stream>>>(
      xn, LC, 128, CC, ipw, 0, 2*DD*DD, xdz, 4*LD, LD, DD, DD, DD, nullptr);

  k_conv<<<dim3(128,32), 256, 0, stream>>>(xdz, cw, cb, ub);

  // G2: pd[z][l][0:130] = u @ W2^T (NF=5 tile, cols>=130 guarded)
  k_mfma<5,0,true><<<dim3(32,1,32), 256, 0, stream>>>(
      ub, 4*LD, LD, DD, w2, 0, 132*DD, pd, 4*LPD, LPD, 132, DD, 130, nullptr);

  k_scanA<<<dim3(NCHUNK,32), 128, 0, stream>>>(pd, ub, dtpb, alog, Pb, Qb);
  k_scanB<<<32, 128, 0, stream>>>(Pb, Qb, hin);
  k_scanC<<<dim3(NCHUNK,32), 128, 0, stream>>>(pd, ub, dtpb, alog, dsp, hin);

  // G1b: zsilu = silu(xn @ ipw[g][128:256]) -> xdz
  k_mfma<4,1,false><<<dim3(32,1,32), 256, 0, stream>>>(
      xn, LC, 128, CC, ipw + DD*DD, 0, 2*DD*DD, xdz, 4*LD, LD, DD, DD, DD, nullptr);

  // LN over D * zsilu -> ynz (into ub)
  k_yln<<<32768, 256, 0, stream>>>(pd, xdz, ong, onb, ub);

  // G3: ygrp[b][l][g*128+n] = ynz @ opw[g]^T  (into pd as (B,L,C))
  k_mfma<4,0,false><<<dim3(32,1,32), 256, 0, stream>>>(
      ub, 4*LD, LD, DD, opw, 0, DD*DD, pd, LC, 128, CC, DD, DD, nullptr);

  // merge + LN over C, in-place on pd (B,L,C)
  k_ln2r<<<8192, 256, 0, stream>>>(pd, xn, gate, ln_g, ln_b, skp);

  // G4: out[b][c][l] = proj_w[c,:] . xmn[b][l][:] + pjb[c]  (A=pjw M=512, B=xmn N=4096)
  k_mfma<4,2,false><<<dim3(4,32,BB), 256, 0, stream>>>(
      pjw, 0, 0, CC, pd, 4*LC, LC, (float*)d_out, 4*(long long)CC*LDIM, (long long)CC*LDIM, LDIM, CC, LDIM, pjb);

  (void)in_sizes; (void)n_in; (void)out_size; (void)ws_size;
}

// Round 6
// 711.012 us; speedup vs baseline: 1.8423x; 1.2986x over previous
//
#include <hip/hip_runtime.h>
#include <hip/hip_bf16.h>
#include <cmath>

#define LDIM 4096
#define BB 8
#define CC 512
#define GG 4
#define DD 128
#define NCHUNK 64
#define CLEN 64    // LDIM / NCHUNK

typedef __attribute__((ext_vector_type(4))) float f32x4;
typedef __attribute__((ext_vector_type(8))) short short8;
typedef __attribute__((ext_vector_type(4))) short s16x4;

__device__ __forceinline__ float siluf(float x){ return x / (1.0f + expf(-x)); }

// f32 -> bf16 bits, round-to-nearest-even
__device__ __forceinline__ short f2bf(float f){
  union { float f; unsigned u; } v; v.f = f;
  unsigned r = v.u + 0x7FFFu + ((v.u >> 16) & 1u);
  return (short)(r >> 16);
}

// ---------------- fused LN over C + transpose: x (B,C,L) -> xnT (B,L,C); zsum[b,c] += sum_l xn ------
// block: 64 l-values x all 512 c staged in LDS. grid (L/64, B), 256 thr.
__global__ __launch_bounds__(256) void k_ln1t(const float* __restrict__ x,
    const float* __restrict__ lg, const float* __restrict__ lb,
    float* __restrict__ xnT, float* __restrict__ zsum){
  __shared__ float tile[CC][65];     // 133,120 B
  __shared__ float red1[4][64], red2[4][64];
  __shared__ float smu[64], srs[64];
  __shared__ float zpart[4][CC];     // 8 KB
  const int t = threadIdx.x;
  const int b = blockIdx.y;
  const int l0 = blockIdx.x * 64;
  const float* xb = x + (size_t)b*CC*LDIM;

  // load 512c x 64l tile, float4 along l
  for (int i = t; i < CC*16; i += 256){
    const int c = i >> 4, l4 = (i & 15) << 2;
    float4 v = *(const float4*)&xb[(size_t)c*LDIM + l0 + l4];
    tile[c][l4+0]=v.x; tile[c][l4+1]=v.y; tile[c][l4+2]=v.z; tile[c][l4+3]=v.w;
  }
  __syncthreads();

  // stats per l
  {
    const int l = t & 63, part = t >> 6;
    float s=0.f, sq=0.f;
    for (int c = part*128; c < part*128+128; ++c){
      float v = tile[c][l];
      s += v; sq = fmaf(v,v,sq);
    }
    red1[part][l]=s; red2[part][l]=sq;
  }
  __syncthreads();
  if (t < 64){
    float s  = red1[0][t]+red1[1][t]+red1[2][t]+red1[3][t];
    float sq = red2[0][t]+red2[1][t]+red2[2][t]+red2[3][t];
    float mu = s*(1.0f/CC);
    float var = sq*(1.0f/CC) - mu*mu;
    smu[t]=mu; srs[t]=rsqrtf(var + 1e-5f);
  }
  __syncthreads();

  // write transposed + accumulate gate sums
  {
    const int w = t >> 6, lane = t & 63;
    float lgv[8], lbv[8], zacc[8];
    #pragma unroll
    for (int j=0;j<8;j++){ const int c = lane + 64*j; lgv[j]=lg[c]; lbv[j]=lb[c]; zacc[j]=0.f; }
    for (int r = 0; r < 16; ++r){
      const int l = w*16 + r;
      const float mu = smu[l], rs = srs[l];
      float* orow = xnT + ((size_t)b*LDIM + l0 + l)*CC;
      #pragma unroll
      for (int j=0;j<8;j++){
        const int c = lane + 64*j;
        float vn = (tile[c][l]-mu)*rs*lgv[j] + lbv[j];
        orow[c] = vn;
        zacc[j] += vn;
      }
    }
    #pragma unroll
    for (int j=0;j<8;j++) zpart[w][lane + 64*j] = zacc[j];
  }
  __syncthreads();
  for (int c = t; c < CC; c += 256)
    atomicAdd(&zsum[b*CC + c], zpart[0][c]+zpart[1][c]+zpart[2][c]+zpart[3][c]);
}

// ---------------- gate MLP ----------------
__global__ __launch_bounds__(256) void k_gate(const float* __restrict__ zsum,
    const float* __restrict__ f1w, const float* __restrict__ f1b,
    const float* __restrict__ f2w, const float* __restrict__ f2b,
    float* __restrict__ gate){
  const int b = blockIdx.x; const int t = threadIdx.x;
  __shared__ float zs[CC]; __shared__ float hid[32];
  for (int c=t;c<CC;c+=256) zs[c] = zsum[b*CC+c] * (1.0f/LDIM);
  __syncthreads();
  if (t < 32){
    float a = f1b[t];
    for (int c=0;c<CC;c++) a = fmaf(zs[c], f1w[t*CC+c], a);
    hid[t] = a > 0.f ? a : 0.f;
  }
  __syncthreads();
  for (int c=t;c<CC;c+=256){
    float a = f2b[c];
    #pragma unroll
    for (int j=0;j<32;j++) a = fmaf(hid[j], f2w[c*32+j], a);
    gate[b*CC+c] = 1.0f/(1.0f+expf(-a));
  }
}

// ---------------- W2[g] = dt_proj_w @ xp_w[0:8] (128x128), row128 = B-row, row129 = C-row ----------------
__global__ void k_wm(const float* __restrict__ xpw, const float* __restrict__ dtpw,
                     float* __restrict__ w2){
  const int g = blockIdx.x; const int k = threadIdx.x; // 128 threads
  const float* xw = xpw + g*10*DD;
  const float* dw = dtpw + g*DD*8;
  float* w2g = w2 + (size_t)g*132*DD;
  for (int r=0;r<DD;r++){
    float a = 0.f;
    #pragma unroll
    for (int j=0;j<8;j++) a = fmaf(dw[r*8+j], xw[j*DD+k], a);
    w2g[r*DD + k] = a;
  }
  w2g[128*DD + k] = xw[8*DD + k];
  w2g[129*DD + k] = xw[9*DD + k];
}

// ---------------- bf16 MFMA GEMM: out(M x N) = A(M,K) * B(N,K)^T, all row-major k-contig f32 in global ----
// block: 128 x (NF*32), 256 thr = 4 waves (2x2), wave tile 64 x (NF*16). BK=32.
// batch z: Ab = A + (z>>2)*aHi + (z&3)*aLo ; Wb likewise ; Ob likewise.
// EPI: 0 none, 1 silu, 2 +bias[m]. GN: guard col<Nlim (B rows >=Nlim read as 0).
template<int NF, int EPI, bool GN>
__global__ __launch_bounds__(256) void k_mfma(
    const float* __restrict__ A, long long aHi, long long aLo, int lda,
    const float* __restrict__ Bw, long long bHi, long long bLo,
    float* __restrict__ O, long long oHi, long long oLo, int ldo,
    int K, int Nlim, const float* __restrict__ bias){
  constexpr int BN = NF*32;
  constexpr int SPAN = NF*16;
  __shared__ __align__(16) short la[128*32];
  __shared__ __align__(16) short lb[BN*32];
  const int t = threadIdx.x;
  const int z = blockIdx.z;
  const float* Ab = A + (size_t)(z>>2)*aHi + (size_t)(z&3)*aLo + (size_t)blockIdx.x*128*lda;
  const float* Wb = Bw + (size_t)(z>>2)*bHi + (size_t)(z&3)*bLo + (size_t)blockIdx.y*BN*K;
  float* Ob = O + (size_t)(z>>2)*oHi + (size_t)(z&3)*oLo;
  const int m0 = blockIdx.x*128, n0 = blockIdx.y*BN;
  const int l = t & 63, w = t >> 6;
  const int wr = w >> 1, wc = w & 1;
  f32x4 acc[4][NF];
  #pragma unroll
  for (int i=0;i<4;i++)
    #pragma unroll
    for (int j=0;j<NF;j++) acc[i][j] = (f32x4){0.f,0.f,0.f,0.f};

  for (int k0 = 0; k0 < K; k0 += 32){
    #pragma unroll
    for (int i=0;i<4;i++){           // A tile: 128 rows x 32k
      const int idx = t + 256*i;
      const int r = idx >> 3, kq = idx & 7;
      float4 v = *(const float4*)&Ab[(size_t)r*lda + k0 + kq*4];
      const int e = r*32 + ((((kq>>1) ^ ((r>>1)&3)))<<3) + ((kq&1)<<2);
      *(s16x4*)&la[e] = (s16x4){f2bf(v.x), f2bf(v.y), f2bf(v.z), f2bf(v.w)};
    }
    #pragma unroll
    for (int i=0;i<NF;i++){          // B tile: BN rows x 32k
      const int idx = t + 256*i;
      const int r = idx >> 3, kq = idx & 7;
      float4 v = make_float4(0.f,0.f,0.f,0.f);
      if (!GN || r < Nlim) v = *(const float4*)&Wb[(size_t)r*K + k0 + kq*4];
      const int e = r*32 + ((((kq>>1) ^ ((r>>1)&3)))<<3) + ((kq&1)<<2);
      *(s16x4*)&lb[e] = (s16x4){f2bf(v.x), f2bf(v.y), f2bf(v.z), f2bf(v.w)};
    }
    __syncthreads();
    short8 af[4], bf[NF];
    #pragma unroll
    for (int mf=0; mf<4; mf++){
      const int R = wr*64 + mf*16 + (l&15);
      const int q = (l>>4) ^ ((R>>1)&3);
      af[mf] = *(const short8*)&la[R*32 + q*8];
    }
    #pragma unroll
    for (int nf=0; nf<NF; nf++){
      const int R = wc*SPAN + nf*16 + (l&15);
      const int q = (l>>4) ^ ((R>>1)&3);
      bf[nf] = *(const short8*)&lb[R*32 + q*8];
    }
    #pragma unroll
    for (int mf=0; mf<4; mf++)
      #pragma unroll
      for (int nf=0; nf<NF; nf++)
        acc[mf][nf] = __builtin_amdgcn_mfma_f32_16x16x32_bf16(af[mf], bf[nf], acc[mf][nf], 0, 0, 0);
    __syncthreads();
  }

  #pragma unroll
  for (int mf=0; mf<4; mf++){
    #pragma unroll
    for (int j=0;j<4;j++){
      const int m = m0 + wr*64 + mf*16 + ((l>>4)<<2) + j;
      const float bv = (EPI==2) ? bias[m] : 0.f;
      #pragma unroll
      for (int nf=0; nf<NF; nf++){
        const int n = n0 + wc*SPAN + nf*16 + (l&15);
        if (GN && n >= Nlim) continue;
        float v = acc[mf][nf][j];
        if (EPI==1) v = siluf(v);
        if (EPI==2) v += bv;
        Ob[(size_t)m*ldo + n] = v;
      }
    }
  }
}

// ---------------- depthwise 3x3 conv + bias + silu; xd (B*G,L,D) -> u (B*G,L,D) ----------------
__global__ __launch_bounds__(256) void k_conv(const float* __restrict__ xd,
    const float* __restrict__ cw, const float* __restrict__ cb, float* __restrict__ u){
  const int z = blockIdx.y; const int g = z & 3;
  const int d = threadIdx.x & 127;
  const int li = threadIdx.x >> 7;
  const int l0 = blockIdx.x * 32;
  float w[9];
  #pragma unroll
  for (int q=0;q<9;q++) w[q] = cw[(g*DD + d)*9 + q];
  const float bsv = cb[g*DD + d];
  const float* xb = xd + (size_t)z*LDIM*DD;
  float* ubp = u + (size_t)z*LDIM*DD;
  for (int ll=li; ll<32; ll+=2){
    const int l = l0 + ll;
    const int h = l >> 6, wc = l & 63;
    float a = bsv;
    #pragma unroll
    for (int ky=0;ky<3;ky++){
      const int hh = h + ky - 1;
      if (hh < 0 || hh >= 64) continue;
      #pragma unroll
      for (int kx=0;kx<3;kx++){
        const int wq = wc + kx - 1;
        if (wq < 0 || wq >= 64) continue;
        a = fmaf(xb[(size_t)(hh*64+wq)*DD + d], w[ky*3+kx], a);
      }
    }
    ubp[(size_t)l*DD + d] = siluf(a);
  }
}

// scan-space -> memory-space index map
__device__ __forceinline__ int scan_lmem(int g0, int ls){
  int j = (g0 >= 2) ? (LDIM-1-ls) : ls;
  return (g0 & 1) ? (((j & 63)<<6) + (j >> 6)) : j;
}

// ---------------- scan phase A ----------------
__global__ __launch_bounds__(128) void k_scanA(const float* __restrict__ pd,
    const float* __restrict__ u, const float* __restrict__ dtb,
    const float* __restrict__ alog, float* __restrict__ P, float* __restrict__ Q){
  const int z = blockIdx.y; const int g = z & 3; const int ch = blockIdx.x;
  const int d = threadIdx.x;
  const float bv = dtb[g*DD + d];
  const float Ad = -expf(alog[g*DD + d]);
  const float* pdb = pd + (size_t)z*LDIM*132;
  const float* ubp = u + (size_t)z*LDIM*DD;
  float Pp = 1.f, q = 0.f;
  for (int i=0;i<CLEN;i++){
    const int lm = scan_lmem(g, ch*CLEN + i);
    const float* row = pdb + (size_t)lm*132;
    float pre = row[d];
    float Bm  = row[128];
    float uv  = ubp[(size_t)lm*DD + d];
    float xa = pre + bv;
    float delta = (xa > 20.f) ? xa : log1pf(expf(xa));
    float dA = expf(Ad * delta);
    Pp *= dA;
    q = fmaf(dA, q, delta * uv * Bm);
  }
  const int idx = (z*NCHUNK + ch)*DD + d;
  P[idx] = Pp; Q[idx] = q;
}

// ---------------- scan phase B ----------------
__global__ __launch_bounds__(128) void k_scanB(const float* __restrict__ P,
    const float* __restrict__ Q, float* __restrict__ hin){
  const int z = blockIdx.x; const int d = threadIdx.x;
  float h = 0.f;
  for (int j=0;j<NCHUNK;j++){
    const int idx = (z*NCHUNK + j)*DD + d;
    hin[idx] = h;
    h = fmaf(P[idx], h, Q[idx]);
  }
}

// ---------------- scan phase C ----------------
__global__ __launch_bounds__(128) void k_scanC(float* __restrict__ pd,
    const float* __restrict__ u, const float* __restrict__ dtb,
    const float* __restrict__ alog, const float* __restrict__ dsp,
    const float* __restrict__ hin){
  const int z = blockIdx.y; const int g = z & 3; const int ch = blockIdx.x;
  const int d = threadIdx.x;
  const float bv = dtb[g*DD + d];
  const float Ad = -expf(alog[g*DD + d]);
  const float Dv = dsp[g*DD + d];
  float* pdb = pd + (size_t)z*LDIM*132;
  const float* ubp = u + (size_t)z*LDIM*DD;
  float h = hin[(z*NCHUNK + ch)*DD + d];
  for (int i=0;i<CLEN;i++){
    const int lm = scan_lmem(g, ch*CLEN + i);
    float* row = pdb + (size_t)lm*132;
    float pre = row[d];
    float Bm  = row[128];
    float Cm  = row[129];
    float uv  = ubp[(size_t)lm*DD + d];
    float xa = pre + bv;
    float delta = (xa > 20.f) ? xa : log1pf(expf(xa));
    float dA = expf(Ad * delta);
    h = fmaf(dA, h, delta * uv * Bm);
    row[d] = fmaf(h, Cm, Dv * uv);
  }
}

// ---------------- LN over D=128 per row (stride 132) * zsilu -> ynz (stride 128) ----------------
__global__ __launch_bounds__(256) void k_yln(const float* __restrict__ y,
    const float* __restrict__ zs, const float* __restrict__ og,
    const float* __restrict__ ob, float* __restrict__ ynz){
  const int row = blockIdx.x*4 + (threadIdx.x >> 6);
  const int lane = threadIdx.x & 63;
  const int g = (row >> 12) & 3;
  const float* r = y + (size_t)row*132;
  float v0 = r[lane], v1 = r[lane+64];
  float s = v0+v1, sq = fmaf(v0,v0, v1*v1);
  #pragma unroll
  for (int o=32;o;o>>=1){ s += __shfl_xor(s,o,64); sq += __shfl_xor(sq,o,64); }
  const float mu = s*(1.0f/DD);
  const float var = sq*(1.0f/DD) - mu*mu;
  const float rs = rsqrtf(var + 1e-5f);
  const size_t base = (size_t)row*DD;
  float o0 = (v0-mu)*rs*og[g*DD+lane]    + ob[g*DD+lane];
  float o1 = (v1-mu)*rs*og[g*DD+lane+64] + ob[g*DD+lane+64];
  ynz[base+lane]    = o0 * zs[base+lane];
  ynz[base+lane+64] = o1 * zs[base+lane+64];
}

// ---------------- final merge on (B,L,C): xm = ygrp*skip*xn*gate, LN over C, in-place. 1 wave/row ----
__global__ __launch_bounds__(256) void k_ln2r(float* __restrict__ yg,
    const float* __restrict__ xnT, const float* __restrict__ gate,
    const float* __restrict__ lg, const float* __restrict__ lb,
    const float* __restrict__ skp){
  const int row = blockIdx.x*4 + (threadIdx.x >> 6);   // (b,l) row, 0..32767
  const int b = row >> 12;
  const int lane = threadIdx.x & 63;
  const float sk = skp[0];
  float* yr = yg + (size_t)row*CC;
  const float* xr = xnT + (size_t)row*CC;
  const float* gb = gate + b*CC;
  float v[8]; float s=0.f, sq=0.f;
  #pragma unroll
  for (int i=0;i<8;i++){
    const int c = lane + 64*i;
    float val = yr[c] * sk * xr[c] * gb[c];
    v[i] = val; s += val; sq = fmaf(val,val,sq);
  }
  #pragma unroll
  for (int o=32;o;o>>=1){ s += __shfl_xor(s,o,64); sq += __shfl_xor(sq,o,64); }
  const float mu = s*(1.0f/CC);
  const float var = sq*(1.0f/CC) - mu*mu;
  const float rs = rsqrtf(var + 1e-5f);
  #pragma unroll
  for (int i=0;i<8;i++){
    const int c = lane + 64*i;
    yr[c] = (v[i]-mu)*rs*lg[c] + lb[c];
  }
}

extern "C" void kernel_launch(void* const* d_in, const int* in_sizes, int n_in,
                              void* d_out, int out_size, void* d_ws, size_t ws_size,
                              hipStream_t stream) {
  const float* x    = (const float*)d_in[0];
  const float* ln_g = (const float*)d_in[1];
  const float* ln_b = (const float*)d_in[2];
  const float* f1w  = (const float*)d_in[3];
  const float* f1b  = (const float*)d_in[4];
  const float* f2w  = (const float*)d_in[5];
  const float* f2b  = (const float*)d_in[6];
  const float* ipw  = (const float*)d_in[7];
  const float* cw   = (const float*)d_in[8];
  const float* cb   = (const float*)d_in[9];
  const float* xpw  = (const float*)d_in[10];
  const float* dtpw = (const float*)d_in[11];
  const float* dtpb = (const float*)d_in[12];
  const float* alog = (const float*)d_in[13];
  const float* dsp  = (const float*)d_in[14];
  const float* ong  = (const float*)d_in[15];
  const float* onb  = (const float*)d_in[16];
  const float* opw  = (const float*)d_in[17];
  const float* pjw  = (const float*)d_in[18];
  const float* pjb  = (const float*)d_in[19];
  const float* skp  = (const float*)d_in[20];

  float* ws   = (float*)d_ws;
  float* xn   = ws;                       // (B,L,C) fused LN+transpose output
  float* ub   = ws + 16777216;            // (B*G,L,128) u / later ynz
  float* pd   = ws + 33554432;            // (B*G,L,132) pd/y -> (B,L,C) ygrp/xmn
  float* zsum = ws + 50855936;            // 4096
  float* gate = ws + 50860032;            // 4096
  float* w2   = ws + 50864128;            // 4*132*128
  float* xdz  = (float*)d_out;            // xd -> P/Q/hin scan scratch -> zsilu
  float* Pb   = xdz;                      // 262144 (NCHUNK=64)
  float* Qb   = xdz + 262144;             // 262144
  float* hin  = xdz + 524288;             // 262144

  const long long LC  = (long long)LDIM*CC;     // 2M
  const long long LD  = (long long)LDIM*DD;     // 512K
  const long long LPD = (long long)LDIM*132;

  hipMemsetAsync(zsum, 0, 4096*sizeof(float), stream);

  // fused LN over C + transpose -> xn (B,L,C), + gate channel sums
  k_ln1t<<<dim3(64, BB), 256, 0, stream>>>(x, ln_g, ln_b, xn, zsum);
  k_gate<<<BB, 256, 0, stream>>>(zsum, f1w, f1b, f2w, f2b, gate);
  k_wm<<<GG, 128, 0, stream>>>(xpw, dtpw, w2);

  // G1a: xd[z][l][d] = xn[b][l][g*128+k] @ ipw[g][0:128]
  k_mfma<4,0,false><<<dim3(32,1,32), 256, 0, stream>>>(
      xn, LC, 128, CC, ipw, 0, 2*DD*DD, xdz, 4*LD, LD, DD, DD, DD, nullptr);

  k_conv<<<dim3(128,32), 256, 0, stream>>>(xdz, cw, cb, ub);

  // G2: pd[z][l][0:130] = u @ W2^T (NF=5 tile, cols>=130 guarded)
  k_mfma<5,0,true><<<dim3(32,1,32), 256, 0, stream>>>(
      ub, 4*LD, LD, DD, w2, 0, 132*DD, pd, 4*LPD, LPD, 132, DD, 130, nullptr);

  // chunked selective scan (P/Q/hin live in d_out scratch; xd already consumed)
  k_scanA<<<dim3(NCHUNK,32), 128, 0, stream>>>(pd, ub, dtpb, alog, Pb, Qb);
  k_scanB<<<32, 128, 0, stream>>>(Pb, Qb, hin);
  k_scanC<<<dim3(NCHUNK,32), 128, 0, stream>>>(pd, ub, dtpb, alog, dsp, hin);

  // G1b: zsilu = silu(xn @ ipw[g][128:256]) -> xdz
  k_mfma<4,1,false><<<dim3(32,1,32), 256, 0, stream>>>(
      xn, LC, 128, CC, ipw + DD*DD, 0, 2*DD*DD, xdz, 4*LD, LD, DD, DD, DD, nullptr);

  // LN over D * zsilu -> ynz (into ub)
  k_yln<<<32768, 256, 0, stream>>>(pd, xdz, ong, onb, ub);

  // G3: ygrp[b][l][g*128+n] = ynz @ opw[g]^T  (into pd as (B,L,C))
  k_mfma<4,0,false><<<dim3(32,1,32), 256, 0, stream>>>(
      ub, 4*LD, LD, DD, opw, 0, DD*DD, pd, LC, 128, CC, DD, DD, nullptr);

  // merge + LN over C, in-place on pd (B,L,C)
  k_ln2r<<<8192, 256, 0, stream>>>(pd, xn, gate, ln_g, ln_b, skp);

  // G4: out[b][c][l] = proj_w[c,:] . xmn[b][l][:] + pjb[c]  (A=pjw M=512, B=xmn N=4096)
  k_mfma<4,2,false><<<dim3(4,32,BB), 256, 0, stream>>>(
      pjw, 0, 0, CC, pd, 4*LC, LC, (float*)d_out, 4*(long long)CC*LDIM, (long long)CC*LDIM, LDIM, CC, LDIM, pjb);

  (void)in_sizes; (void)n_in; (void)out_size; (void)ws_size;
}

// Round 7
// 657.703 us; speedup vs baseline: 1.9916x; 1.0811x over previous
//
#include <hip/hip_runtime.h>
#include <hip/hip_bf16.h>
#include <cmath>

#define LDIM 4096
#define BB 8
#define CC 512
#define GG 4
#define DD 128
#define NCHUNK 64
#define CLEN 64    // LDIM / NCHUNK

typedef __attribute__((ext_vector_type(4))) float f32x4;
typedef __attribute__((ext_vector_type(8))) short short8;
typedef __attribute__((ext_vector_type(4))) short s16x4;

__device__ __forceinline__ float siluf(float x){ return x / (1.0f + expf(-x)); }

// f32 -> bf16 bits, round-to-nearest-even
__device__ __forceinline__ short f2bf(float f){
  union { float f; unsigned u; } v; v.f = f;
  unsigned r = v.u + 0x7FFFu + ((v.u >> 16) & 1u);
  return (short)(r >> 16);
}

// ---------------- fused LN over C + transpose: x (B,C,L) -> xnT (B,L,C); zsum[b,c] += sum_l xn ------
__global__ __launch_bounds__(256) void k_ln1t(const float* __restrict__ x,
    const float* __restrict__ lg, const float* __restrict__ lb,
    float* __restrict__ xnT, float* __restrict__ zsum){
  __shared__ float tile[CC][65];     // 133,120 B
  __shared__ float red1[4][64], red2[4][64];
  __shared__ float smu[64], srs[64];
  __shared__ float zpart[4][CC];     // 8 KB
  const int t = threadIdx.x;
  const int b = blockIdx.y;
  const int l0 = blockIdx.x * 64;
  const float* xb = x + (size_t)b*CC*LDIM;

  for (int i = t; i < CC*16; i += 256){
    const int c = i >> 4, l4 = (i & 15) << 2;
    float4 v = *(const float4*)&xb[(size_t)c*LDIM + l0 + l4];
    tile[c][l4+0]=v.x; tile[c][l4+1]=v.y; tile[c][l4+2]=v.z; tile[c][l4+3]=v.w;
  }
  __syncthreads();

  {
    const int l = t & 63, part = t >> 6;
    float s=0.f, sq=0.f;
    for (int c = part*128; c < part*128+128; ++c){
      float v = tile[c][l];
      s += v; sq = fmaf(v,v,sq);
    }
    red1[part][l]=s; red2[part][l]=sq;
  }
  __syncthreads();
  if (t < 64){
    float s  = red1[0][t]+red1[1][t]+red1[2][t]+red1[3][t];
    float sq = red2[0][t]+red2[1][t]+red2[2][t]+red2[3][t];
    float mu = s*(1.0f/CC);
    float var = sq*(1.0f/CC) - mu*mu;
    smu[t]=mu; srs[t]=rsqrtf(var + 1e-5f);
  }
  __syncthreads();

  {
    const int w = t >> 6, lane = t & 63;
    float lgv[8], lbv[8], zacc[8];
    #pragma unroll
    for (int j=0;j<8;j++){ const int c = lane + 64*j; lgv[j]=lg[c]; lbv[j]=lb[c]; zacc[j]=0.f; }
    for (int r = 0; r < 16; ++r){
      const int l = w*16 + r;
      const float mu = smu[l], rs = srs[l];
      float* orow = xnT + ((size_t)b*LDIM + l0 + l)*CC;
      #pragma unroll
      for (int j=0;j<8;j++){
        const int c = lane + 64*j;
        float vn = (tile[c][l]-mu)*rs*lgv[j] + lbv[j];
        orow[c] = vn;
        zacc[j] += vn;
      }
    }
    #pragma unroll
    for (int j=0;j<8;j++) zpart[w][lane + 64*j] = zacc[j];
  }
  __syncthreads();
  for (int c = t; c < CC; c += 256)
    atomicAdd(&zsum[b*CC + c], zpart[0][c]+zpart[1][c]+zpart[2][c]+zpart[3][c]);
}

// ---------------- gate MLP ----------------
__global__ __launch_bounds__(256) void k_gate(const float* __restrict__ zsum,
    const float* __restrict__ f1w, const float* __restrict__ f1b,
    const float* __restrict__ f2w, const float* __restrict__ f2b,
    float* __restrict__ gate){
  const int b = blockIdx.x; const int t = threadIdx.x;
  __shared__ float zs[CC]; __shared__ float hid[32];
  for (int c=t;c<CC;c+=256) zs[c] = zsum[b*CC+c] * (1.0f/LDIM);
  __syncthreads();
  if (t < 32){
    float a = f1b[t];
    for (int c=0;c<CC;c++) a = fmaf(zs[c], f1w[t*CC+c], a);
    hid[t] = a > 0.f ? a : 0.f;
  }
  __syncthreads();
  for (int c=t;c<CC;c+=256){
    float a = f2b[c];
    #pragma unroll
    for (int j=0;j<32;j++) a = fmaf(hid[j], f2w[c*32+j], a);
    gate[b*CC+c] = 1.0f/(1.0f+expf(-a));
  }
}

// ---------------- W2[g] = dt_proj_w @ xp_w[0:8] (128x128), row128 = B-row, row129 = C-row ----------------
__global__ void k_wm(const float* __restrict__ xpw, const float* __restrict__ dtpw,
                     float* __restrict__ w2){
  const int g = blockIdx.x; const int k = threadIdx.x; // 128 threads
  const float* xw = xpw + g*10*DD;
  const float* dw = dtpw + g*DD*8;
  float* w2g = w2 + (size_t)g*132*DD;
  for (int r=0;r<DD;r++){
    float a = 0.f;
    #pragma unroll
    for (int j=0;j<8;j++) a = fmaf(dw[r*8+j], xw[j*DD+k], a);
    w2g[r*DD + k] = a;
  }
  w2g[128*DD + k] = xw[8*DD + k];
  w2g[129*DD + k] = xw[9*DD + k];
}

// ---------------- bf16 MFMA GEMM (see prior rounds for layout docs) ----------------
template<int NF, int EPI, bool GN>
__global__ __launch_bounds__(256) void k_mfma(
    const float* __restrict__ A, long long aHi, long long aLo, int lda,
    const float* __restrict__ Bw, long long bHi, long long bLo,
    float* __restrict__ O, long long oHi, long long oLo, int ldo,
    int K, int Nlim, const float* __restrict__ bias){
  constexpr int BN = NF*32;
  constexpr int SPAN = NF*16;
  __shared__ __align__(16) short la[128*32];
  __shared__ __align__(16) short lb[BN*32];
  const int t = threadIdx.x;
  const int z = blockIdx.z;
  const float* Ab = A + (size_t)(z>>2)*aHi + (size_t)(z&3)*aLo + (size_t)blockIdx.x*128*lda;
  const float* Wb = Bw + (size_t)(z>>2)*bHi + (size_t)(z&3)*bLo + (size_t)blockIdx.y*BN*K;
  float* Ob = O + (size_t)(z>>2)*oHi + (size_t)(z&3)*oLo;
  const int m0 = blockIdx.x*128, n0 = blockIdx.y*BN;
  const int l = t & 63, w = t >> 6;
  const int wr = w >> 1, wc = w & 1;
  f32x4 acc[4][NF];
  #pragma unroll
  for (int i=0;i<4;i++)
    #pragma unroll
    for (int j=0;j<NF;j++) acc[i][j] = (f32x4){0.f,0.f,0.f,0.f};

  for (int k0 = 0; k0 < K; k0 += 32){
    #pragma unroll
    for (int i=0;i<4;i++){           // A tile: 128 rows x 32k
      const int idx = t + 256*i;
      const int r = idx >> 3, kq = idx & 7;
      float4 v = *(const float4*)&Ab[(size_t)r*lda + k0 + kq*4];
      const int e = r*32 + ((((kq>>1) ^ ((r>>1)&3)))<<3) + ((kq&1)<<2);
      *(s16x4*)&la[e] = (s16x4){f2bf(v.x), f2bf(v.y), f2bf(v.z), f2bf(v.w)};
    }
    #pragma unroll
    for (int i=0;i<NF;i++){          // B tile: BN rows x 32k
      const int idx = t + 256*i;
      const int r = idx >> 3, kq = idx & 7;
      float4 v = make_float4(0.f,0.f,0.f,0.f);
      if (!GN || r < Nlim) v = *(const float4*)&Wb[(size_t)r*K + k0 + kq*4];
      const int e = r*32 + ((((kq>>1) ^ ((r>>1)&3)))<<3) + ((kq&1)<<2);
      *(s16x4*)&lb[e] = (s16x4){f2bf(v.x), f2bf(v.y), f2bf(v.z), f2bf(v.w)};
    }
    __syncthreads();
    short8 af[4], bf[NF];
    #pragma unroll
    for (int mf=0; mf<4; mf++){
      const int R = wr*64 + mf*16 + (l&15);
      const int q = (l>>4) ^ ((R>>1)&3);
      af[mf] = *(const short8*)&la[R*32 + q*8];
    }
    #pragma unroll
    for (int nf=0; nf<NF; nf++){
      const int R = wc*SPAN + nf*16 + (l&15);
      const int q = (l>>4) ^ ((R>>1)&3);
      bf[nf] = *(const short8*)&lb[R*32 + q*8];
    }
    #pragma unroll
    for (int mf=0; mf<4; mf++)
      #pragma unroll
      for (int nf=0; nf<NF; nf++)
        acc[mf][nf] = __builtin_amdgcn_mfma_f32_16x16x32_bf16(af[mf], bf[nf], acc[mf][nf], 0, 0, 0);
    __syncthreads();
  }

  #pragma unroll
  for (int mf=0; mf<4; mf++){
    #pragma unroll
    for (int j=0;j<4;j++){
      const int m = m0 + wr*64 + mf*16 + ((l>>4)<<2) + j;
      const float bv = (EPI==2) ? bias[m] : 0.f;
      #pragma unroll
      for (int nf=0; nf<NF; nf++){
        const int n = n0 + wc*SPAN + nf*16 + (l&15);
        if (GN && n >= Nlim) continue;
        float v = acc[mf][nf][j];
        if (EPI==1) v = siluf(v);
        if (EPI==2) v += bv;
        Ob[(size_t)m*ldo + n] = v;
      }
    }
  }
}

// ---------------- depthwise 3x3 conv + bias + silu, vectorized d x4, register-sliding w ----------------
// grid (64 h, 32 z), 256 thr: (t&31) -> 4 d's, (t>>5) -> 8 consecutive w's.
__global__ __launch_bounds__(256) void k_conv(const float* __restrict__ xd,
    const float* __restrict__ cw, const float* __restrict__ cb, float* __restrict__ u){
  const int z = blockIdx.y; const int g = z & 3;
  const int h = blockIdx.x;
  const int t = threadIdx.x;
  const int d4 = (t & 31) << 2;
  const int w0 = (t >> 5) << 3;
  float4 wv[9];
  #pragma unroll
  for (int q=0;q<9;q++){
    wv[q].x = cw[(g*DD + d4+0)*9 + q];
    wv[q].y = cw[(g*DD + d4+1)*9 + q];
    wv[q].z = cw[(g*DD + d4+2)*9 + q];
    wv[q].w = cw[(g*DD + d4+3)*9 + q];
  }
  float4 bs;
  bs.x = cb[g*DD+d4]; bs.y = cb[g*DD+d4+1]; bs.z = cb[g*DD+d4+2]; bs.w = cb[g*DD+d4+3];
  const float* xb = xd + (size_t)z*LDIM*DD;
  float* ub = u + (size_t)z*LDIM*DD;
  const bool hm = (h > 0), hp = (h < 63);
  const float4 Z = make_float4(0.f,0.f,0.f,0.f);

  // col registers for rows h-1,h,h+1 at w-1 (c0) and w (c1)
  float4 c0[3], c1[3], c2[3];
  #pragma unroll
  for (int r=0;r<3;r++){
    const int hh = h + r - 1;
    const bool rv = (r==0) ? hm : ((r==2) ? hp : true);
    c0[r] = (rv && w0 > 0) ? *(const float4*)&xb[(size_t)((hh<<6) + w0-1)*DD + d4] : Z;
    c1[r] = rv             ? *(const float4*)&xb[(size_t)((hh<<6) + w0  )*DD + d4] : Z;
  }

  #pragma unroll
  for (int ww=0; ww<8; ww++){
    const int wc = w0 + ww;
    #pragma unroll
    for (int r=0;r<3;r++){
      const int hh = h + r - 1;
      const bool rv = (r==0) ? hm : ((r==2) ? hp : true);
      c2[r] = (rv && wc < 63) ? *(const float4*)&xb[(size_t)((hh<<6) + wc+1)*DD + d4] : Z;
    }
    float4 a = bs;
    #pragma unroll
    for (int r=0;r<3;r++){
      a.x = fmaf(c0[r].x, wv[r*3+0].x, fmaf(c1[r].x, wv[r*3+1].x, fmaf(c2[r].x, wv[r*3+2].x, a.x)));
      a.y = fmaf(c0[r].y, wv[r*3+0].y, fmaf(c1[r].y, wv[r*3+1].y, fmaf(c2[r].y, wv[r*3+2].y, a.y)));
      a.z = fmaf(c0[r].z, wv[r*3+0].z, fmaf(c1[r].z, wv[r*3+1].z, fmaf(c2[r].z, wv[r*3+2].z, a.z)));
      a.w = fmaf(c0[r].w, wv[r*3+0].w, fmaf(c1[r].w, wv[r*3+1].w, fmaf(c2[r].w, wv[r*3+2].w, a.w)));
    }
    a.x = siluf(a.x); a.y = siluf(a.y); a.z = siluf(a.z); a.w = siluf(a.w);
    *(float4*)&ub[(size_t)((h<<6) + wc)*DD + d4] = a;
    #pragma unroll
    for (int r=0;r<3;r++){ c0[r] = c1[r]; c1[r] = c2[r]; }
  }
}

// scan-space -> memory-space index map
__device__ __forceinline__ int scan_lmem(int g0, int ls){
  int j = (g0 >= 2) ? (LDIM-1-ls) : ls;
  return (g0 & 1) ? (((j & 63)<<6) + (j >> 6)) : j;
}

// ---------------- scan phase A ----------------
__global__ __launch_bounds__(128) void k_scanA(const float* __restrict__ pd,
    const float* __restrict__ u, const float* __restrict__ dtb,
    const float* __restrict__ alog, float* __restrict__ P, float* __restrict__ Q){
  const int z = blockIdx.y; const int g = z & 3; const int ch = blockIdx.x;
  const int d = threadIdx.x;
  const float bv = dtb[g*DD + d];
  const float Ad = -expf(alog[g*DD + d]);
  const float* pdb = pd + (size_t)z*LDIM*132;
  const float* ubp = u + (size_t)z*LDIM*DD;
  float Pp = 1.f, q = 0.f;
  for (int i=0;i<CLEN;i++){
    const int lm = scan_lmem(g, ch*CLEN + i);
    const float* row = pdb + (size_t)lm*132;
    float pre = row[d];
    float Bm  = row[128];
    float uv  = ubp[(size_t)lm*DD + d];
    float xa = pre + bv;
    float delta = (xa > 20.f) ? xa : log1pf(expf(xa));
    float dA = expf(Ad * delta);
    Pp *= dA;
    q = fmaf(dA, q, delta * uv * Bm);
  }
  const int idx = (z*NCHUNK + ch)*DD + d;
  P[idx] = Pp; Q[idx] = q;
}

// ---------------- scan phase B ----------------
__global__ __launch_bounds__(128) void k_scanB(const float* __restrict__ P,
    const float* __restrict__ Q, float* __restrict__ hin){
  const int z = blockIdx.x; const int d = threadIdx.x;
  float h = 0.f;
  for (int j=0;j<NCHUNK;j++){
    const int idx = (z*NCHUNK + j)*DD + d;
    hin[idx] = h;
    h = fmaf(P[idx], h, Q[idx]);
  }
}

// ---------------- scan phase C ----------------
__global__ __launch_bounds__(128) void k_scanC(float* __restrict__ pd,
    const float* __restrict__ u, const float* __restrict__ dtb,
    const float* __restrict__ alog, const float* __restrict__ dsp,
    const float* __restrict__ hin){
  const int z = blockIdx.y; const int g = z & 3; const int ch = blockIdx.x;
  const int d = threadIdx.x;
  const float bv = dtb[g*DD + d];
  const float Ad = -expf(alog[g*DD + d]);
  const float Dv = dsp[g*DD + d];
  float* pdb = pd + (size_t)z*LDIM*132;
  const float* ubp = u + (size_t)z*LDIM*DD;
  float h = hin[(z*NCHUNK + ch)*DD + d];
  for (int i=0;i<CLEN;i++){
    const int lm = scan_lmem(g, ch*CLEN + i);
    float* row = pdb + (size_t)lm*132;
    float pre = row[d];
    float Bm  = row[128];
    float Cm  = row[129];
    float uv  = ubp[(size_t)lm*DD + d];
    float xa = pre + bv;
    float delta = (xa > 20.f) ? xa : log1pf(expf(xa));
    float dA = expf(Ad * delta);
    h = fmaf(dA, h, delta * uv * Bm);
    row[d] = fmaf(h, Cm, Dv * uv);
  }
}

// ---------------- LN over D=128 per row (stride 132) * zsilu -> ynz (stride 128) ----------------
__global__ __launch_bounds__(256) void k_yln(const float* __restrict__ y,
    const float* __restrict__ zs, const float* __restrict__ og,
    const float* __restrict__ ob, float* __restrict__ ynz){
  const int row = blockIdx.x*4 + (threadIdx.x >> 6);
  const int lane = threadIdx.x & 63;
  const int g = (row >> 12) & 3;
  const float* r = y + (size_t)row*132;
  float v0 = r[lane], v1 = r[lane+64];
  float s = v0+v1, sq = fmaf(v0,v0, v1*v1);
  #pragma unroll
  for (int o=32;o;o>>=1){ s += __shfl_xor(s,o,64); sq += __shfl_xor(sq,o,64); }
  const float mu = s*(1.0f/DD);
  const float var = sq*(1.0f/DD) - mu*mu;
  const float rs = rsqrtf(var + 1e-5f);
  const size_t base = (size_t)row*DD;
  float o0 = (v0-mu)*rs*og[g*DD+lane]    + ob[g*DD+lane];
  float o1 = (v1-mu)*rs*og[g*DD+lane+64] + ob[g*DD+lane+64];
  ynz[base+lane]    = o0 * zs[base+lane];
  ynz[base+lane+64] = o1 * zs[base+lane+64];
}

// ---------------- final merge on (B,L,C): xm = ygrp*skip*xn*gate, LN over C, in-place. 1 wave/row ----
__global__ __launch_bounds__(256) void k_ln2r(float* __restrict__ yg,
    const float* __restrict__ xnT, const float* __restrict__ gate,
    const float* __restrict__ lg, const float* __restrict__ lb,
    const float* __restrict__ skp){
  const int row = blockIdx.x*4 + (threadIdx.x >> 6);   // (b,l) row, 0..32767
  const int b = row >> 12;
  const int lane = threadIdx.x & 63;
  const float sk = skp[0];
  float* yr = yg + (size_t)row*CC;
  const float* xr = xnT + (size_t)row*CC;
  const float* gb = gate + b*CC;
  float v[8]; float s=0.f, sq=0.f;
  #pragma unroll
  for (int i=0;i<8;i++){
    const int c = lane + 64*i;
    float val = yr[c] * sk * xr[c] * gb[c];
    v[i] = val; s += val; sq = fmaf(val,val,sq);
  }
  #pragma unroll
  for (int o=32;o;o>>=1){ s += __shfl_xor(s,o,64); sq += __shfl_xor(sq,o,64); }
  const float mu = s*(1.0f/CC);
  const float var = sq*(1.0f/CC) - mu*mu;
  const float rs = rsqrtf(var + 1e-5f);
  #pragma unroll
  for (int i=0;i<8;i++){
    const int c = lane + 64*i;
    yr[c] = (v[i]-mu)*rs*lg[c] + lb[c];
  }
}

extern "C" void kernel_launch(void* const* d_in, const int* in_sizes, int n_in,
                              void* d_out, int out_size, void* d_ws, size_t ws_size,
                              hipStream_t stream) {
  const float* x    = (const float*)d_in[0];
  const float* ln_g = (const float*)d_in[1];
  const float* ln_b = (const float*)d_in[2];
  const float* f1w  = (const float*)d_in[3];
  const float* f1b  = (const float*)d_in[4];
  const float* f2w  = (const float*)d_in[5];
  const float* f2b  = (const float*)d_in[6];
  const float* ipw  = (const float*)d_in[7];
  const float* cw   = (const float*)d_in[8];
  const float* cb   = (const float*)d_in[9];
  const float* xpw  = (const float*)d_in[10];
  const float* dtpw = (const float*)d_in[11];
  const float* dtpb = (const float*)d_in[12];
  const float* alog = (const float*)d_in[13];
  const float* dsp  = (const float*)d_in[14];
  const float* ong  = (const float*)d_in[15];
  const float* onb  = (const float*)d_in[16];
  const float* opw  = (const float*)d_in[17];
  const float* pjw  = (const float*)d_in[18];
  const float* pjb  = (const float*)d_in[19];
  const float* skp  = (const float*)d_in[20];

  float* ws   = (float*)d_ws;
  float* xn   = ws;                       // (B,L,C) fused LN+transpose output
  float* ub   = ws + 16777216;            // (B*G,L,128) u / later ynz
  float* pd   = ws + 33554432;            // (B*G,L,132) pd/y -> (B,L,C) ygrp/xmn
  float* zsum = ws + 50855936;            // 4096
  float* gate = ws + 50860032;            // 4096
  float* w2   = ws + 50864128;            // 4*132*128
  float* xdz  = (float*)d_out;            // xd -> P/Q/hin scan scratch -> zsilu
  float* Pb   = xdz;                      // 262144 (NCHUNK=64)
  float* Qb   = xdz + 262144;             // 262144
  float* hin  = xdz + 524288;             // 262144

  const long long LC  = (long long)LDIM*CC;     // 2M
  const long long LD  = (long long)LDIM*DD;     // 512K
  const long long LPD = (long long)LDIM*132;

  hipMemsetAsync(zsum, 0, 4096*sizeof(float), stream);

  // fused LN over C + transpose -> xn (B,L,C), + gate channel sums
  k_ln1t<<<dim3(64, BB), 256, 0, stream>>>(x, ln_g, ln_b, xn, zsum);
  k_gate<<<BB, 256, 0, stream>>>(zsum, f1w, f1b, f2w, f2b, gate);
  k_wm<<<GG, 128, 0, stream>>>(xpw, dtpw, w2);

  // G1a: xd[z][l][d] = xn[b][l][g*128+k] @ ipw[g][0:128]
  k_mfma<4,0,false><<<dim3(32,1,32), 256, 0, stream>>>(
      xn, LC, 128, CC, ipw, 0, 2*DD*DD, xdz, 4*LD, LD, DD, DD, DD, nullptr);

  k_conv<<<dim3(64,32), 256, 0, stream>>>(xdz, cw, cb, ub);

  // G2: pd[z][l][0:130] = u @ W2^T (NF=5 tile, cols>=130 guarded)
  k_mfma<5,0,true><<<dim3(32,1,32), 256, 0, stream>>>(
      ub, 4*LD, LD, DD, w2, 0, 132*DD, pd, 4*LPD, LPD, 132, DD, 130, nullptr);

  // chunked selective scan (P/Q/hin live in d_out scratch; xd already consumed)
  k_scanA<<<dim3(NCHUNK,32), 128, 0, stream>>>(pd, ub, dtpb, alog, Pb, Qb);
  k_scanB<<<32, 128, 0, stream>>>(Pb, Qb, hin);
  k_scanC<<<dim3(NCHUNK,32), 128, 0, stream>>>(pd, ub, dtpb, alog, dsp, hin);

  // G1b: zsilu = silu(xn @ ipw[g][128:256]) -> xdz
  k_mfma<4,1,false><<<dim3(32,1,32), 256, 0, stream>>>(
      xn, LC, 128, CC, ipw + DD*DD, 0, 2*DD*DD, xdz, 4*LD, LD, DD, DD, DD, nullptr);

  // LN over D * zsilu -> ynz (into ub)
  k_yln<<<32768, 256, 0, stream>>>(pd, xdz, ong, onb, ub);

  // G3: ygrp[b][l][g*128+n] = ynz @ opw[g]^T  (into pd as (B,L,C))
  k_mfma<4,0,false><<<dim3(32,1,32), 256, 0, stream>>>(
      ub, 4*LD, LD, DD, opw, 0, DD*DD, pd, LC, 128, CC, DD, DD, nullptr);

  // merge + LN over C, in-place on pd (B,L,C)
  k_ln2r<<<8192, 256, 0, stream>>>(pd, xn, gate, ln_g, ln_b, skp);

  // G4: out[b][c][l] = proj_w[c,:] . xmn[b][l][:] + pjb[c]  (A=pjw M=512, B=xmn N=4096)
  k_mfma<4,2,false><<<dim3(4,32,BB), 256, 0, stream>>>(
      pjw, 0, 0, CC, pd, 4*LC, LC, (float*)d_out, 4*(long long)CC*LDIM, (long long)CC*LDIM, LDIM, CC, LDIM, pjb);

  (void)in_sizes; (void)n_in; (void)out_size; (void)ws_size;
}

// Round 10
// 590.800 us; speedup vs baseline: 2.2171x; 1.1132x over previous
//
#include <hip/hip_runtime.h>
#include <hip/hip_bf16.h>
#include <cmath>

#define LDIM 4096
#define BB 8
#define CC 512
#define GG 4
#define DD 128
#define NCHUNK 64
#define CLEN 64    // LDIM / NCHUNK

typedef __attribute__((ext_vector_type(4))) float f32x4;
typedef __attribute__((ext_vector_type(8))) short short8;
typedef __attribute__((ext_vector_type(4))) short s16x4;

__device__ __forceinline__ float siluf(float x){ return x / (1.0f + expf(-x)); }

// f32 -> bf16 bits, round-to-nearest-even
__device__ __forceinline__ short f2bf(float f){
  union { float f; unsigned u; } v; v.f = f;
  unsigned r = v.u + 0x7FFFu + ((v.u >> 16) & 1u);
  return (short)(r >> 16);
}

// ---------------- fused LN over C + transpose: x (B,C,L) -> xnT (B,L,C); zsum[b,c] += sum_l xn ------
__global__ __launch_bounds__(256) void k_ln1t(const float* __restrict__ x,
    const float* __restrict__ lg, const float* __restrict__ lb,
    float* __restrict__ xnT, float* __restrict__ zsum){
  __shared__ float tile[CC][65];     // 133,120 B
  __shared__ float red1[4][64], red2[4][64];
  __shared__ float smu[64], srs[64];
  __shared__ float zpart[4][CC];     // 8 KB
  const int t = threadIdx.x;
  const int b = blockIdx.y;
  const int l0 = blockIdx.x * 64;
  const float* xb = x + (size_t)b*CC*LDIM;

  for (int i = t; i < CC*16; i += 256){
    const int c = i >> 4, l4 = (i & 15) << 2;
    float4 v = *(const float4*)&xb[(size_t)c*LDIM + l0 + l4];
    tile[c][l4+0]=v.x; tile[c][l4+1]=v.y; tile[c][l4+2]=v.z; tile[c][l4+3]=v.w;
  }
  __syncthreads();

  {
    const int l = t & 63, part = t >> 6;
    float s=0.f, sq=0.f;
    for (int c = part*128; c < part*128+128; ++c){
      float v = tile[c][l];
      s += v; sq = fmaf(v,v,sq);
    }
    red1[part][l]=s; red2[part][l]=sq;
  }
  __syncthreads();
  if (t < 64){
    float s  = red1[0][t]+red1[1][t]+red1[2][t]+red1[3][t];
    float sq = red2[0][t]+red2[1][t]+red2[2][t]+red2[3][t];
    float mu = s*(1.0f/CC);
    float var = sq*(1.0f/CC) - mu*mu;
    smu[t]=mu; srs[t]=rsqrtf(var + 1e-5f);
  }
  __syncthreads();

  {
    const int w = t >> 6, lane = t & 63;
    float lgv[8], lbv[8], zacc[8];
    #pragma unroll
    for (int j=0;j<8;j++){ const int c = lane + 64*j; lgv[j]=lg[c]; lbv[j]=lb[c]; zacc[j]=0.f; }
    for (int r = 0; r < 16; ++r){
      const int l = w*16 + r;
      const float mu = smu[l], rs = srs[l];
      float* orow = xnT + ((size_t)b*LDIM + l0 + l)*CC;
      #pragma unroll
      for (int j=0;j<8;j++){
        const int c = lane + 64*j;
        float vn = (tile[c][l]-mu)*rs*lgv[j] + lbv[j];
        orow[c] = vn;
        zacc[j] += vn;
      }
    }
    #pragma unroll
    for (int j=0;j<8;j++) zpart[w][lane + 64*j] = zacc[j];
  }
  __syncthreads();
  for (int c = t; c < CC; c += 256)
    atomicAdd(&zsum[b*CC + c], zpart[0][c]+zpart[1][c]+zpart[2][c]+zpart[3][c]);
}

// ---------------- gate MLP ----------------
__global__ __launch_bounds__(256) void k_gate(const float* __restrict__ zsum,
    const float* __restrict__ f1w, const float* __restrict__ f1b,
    const float* __restrict__ f2w, const float* __restrict__ f2b,
    float* __restrict__ gate){
  const int b = blockIdx.x; const int t = threadIdx.x;
  __shared__ float zs[CC]; __shared__ float hid[32];
  for (int c=t;c<CC;c+=256) zs[c] = zsum[b*CC+c] * (1.0f/LDIM);
  __syncthreads();
  if (t < 32){
    float a = f1b[t];
    for (int c=0;c<CC;c++) a = fmaf(zs[c], f1w[t*CC+c], a);
    hid[t] = a > 0.f ? a : 0.f;
  }
  __syncthreads();
  for (int c=t;c<CC;c+=256){
    float a = f2b[c];
    #pragma unroll
    for (int j=0;j<32;j++) a = fmaf(hid[j], f2w[c*32+j], a);
    gate[b*CC+c] = 1.0f/(1.0f+expf(-a));
  }
}

// ---------------- W2[g] = dt_proj_w @ xp_w[0:8] (128x128), row128 = B-row, row129 = C-row ----------------
__global__ void k_wm(const float* __restrict__ xpw, const float* __restrict__ dtpw,
                     float* __restrict__ w2){
  const int g = blockIdx.x; const int k = threadIdx.x; // 128 threads
  const float* xw = xpw + g*10*DD;
  const float* dw = dtpw + g*DD*8;
  float* w2g = w2 + (size_t)g*132*DD;
  for (int r=0;r<DD;r++){
    float a = 0.f;
    #pragma unroll
    for (int j=0;j<8;j++) a = fmaf(dw[r*8+j], xw[j*DD+k], a);
    w2g[r*DD + k] = a;
  }
  w2g[128*DD + k] = xw[8*DD + k];
  w2g[129*DD + k] = xw[9*DD + k];
}

// ---------------- bf16 MFMA GEMM (see prior rounds for layout docs) ----------------
template<int NF, int EPI, bool GN>
__global__ __launch_bounds__(256) void k_mfma(
    const float* __restrict__ A, long long aHi, long long aLo, int lda,
    const float* __restrict__ Bw, long long bHi, long long bLo,
    float* __restrict__ O, long long oHi, long long oLo, int ldo,
    int K, int Nlim, const float* __restrict__ bias){
  constexpr int BN = NF*32;
  constexpr int SPAN = NF*16;
  __shared__ __align__(16) short la[128*32];
  __shared__ __align__(16) short lb[BN*32];
  const int t = threadIdx.x;
  const int z = blockIdx.z;
  const float* Ab = A + (size_t)(z>>2)*aHi + (size_t)(z&3)*aLo + (size_t)blockIdx.x*128*lda;
  const float* Wb = Bw + (size_t)(z>>2)*bHi + (size_t)(z&3)*bLo + (size_t)blockIdx.y*BN*K;
  float* Ob = O + (size_t)(z>>2)*oHi + (size_t)(z&3)*oLo;
  const int m0 = blockIdx.x*128, n0 = blockIdx.y*BN;
  const int l = t & 63, w = t >> 6;
  const int wr = w >> 1, wc = w & 1;
  f32x4 acc[4][NF];
  #pragma unroll
  for (int i=0;i<4;i++)
    #pragma unroll
    for (int j=0;j<NF;j++) acc[i][j] = (f32x4){0.f,0.f,0.f,0.f};

  for (int k0 = 0; k0 < K; k0 += 32){
    #pragma unroll
    for (int i=0;i<4;i++){           // A tile: 128 rows x 32k
      const int idx = t + 256*i;
      const int r = idx >> 3, kq = idx & 7;
      float4 v = *(const float4*)&Ab[(size_t)r*lda + k0 + kq*4];
      const int e = r*32 + ((((kq>>1) ^ ((r>>1)&3)))<<3) + ((kq&1)<<2);
      *(s16x4*)&la[e] = (s16x4){f2bf(v.x), f2bf(v.y), f2bf(v.z), f2bf(v.w)};
    }
    #pragma unroll
    for (int i=0;i<NF;i++){          // B tile: BN rows x 32k
      const int idx = t + 256*i;
      const int r = idx >> 3, kq = idx & 7;
      float4 v = make_float4(0.f,0.f,0.f,0.f);
      if (!GN || r < Nlim) v = *(const float4*)&Wb[(size_t)r*K + k0 + kq*4];
      const int e = r*32 + ((((kq>>1) ^ ((r>>1)&3)))<<3) + ((kq&1)<<2);
      *(s16x4*)&lb[e] = (s16x4){f2bf(v.x), f2bf(v.y), f2bf(v.z), f2bf(v.w)};
    }
    __syncthreads();
    short8 af[4], bf[NF];
    #pragma unroll
    for (int mf=0; mf<4; mf++){
      const int R = wr*64 + mf*16 + (l&15);
      const int q = (l>>4) ^ ((R>>1)&3);
      af[mf] = *(const short8*)&la[R*32 + q*8];
    }
    #pragma unroll
    for (int nf=0; nf<NF; nf++){
      const int R = wc*SPAN + nf*16 + (l&15);
      const int q = (l>>4) ^ ((R>>1)&3);
      bf[nf] = *(const short8*)&lb[R*32 + q*8];
    }
    #pragma unroll
    for (int mf=0; mf<4; mf++)
      #pragma unroll
      for (int nf=0; nf<NF; nf++)
        acc[mf][nf] = __builtin_amdgcn_mfma_f32_16x16x32_bf16(af[mf], bf[nf], acc[mf][nf], 0, 0, 0);
    __syncthreads();
  }

  #pragma unroll
  for (int mf=0; mf<4; mf++){
    #pragma unroll
    for (int j=0;j<4;j++){
      const int m = m0 + wr*64 + mf*16 + ((l>>4)<<2) + j;
      const float bv = (EPI==2) ? bias[m] : 0.f;
      #pragma unroll
      for (int nf=0; nf<NF; nf++){
        const int n = n0 + wc*SPAN + nf*16 + (l&15);
        if (GN && n >= Nlim) continue;
        float v = acc[mf][nf][j];
        if (EPI==1) v = siluf(v);
        if (EPI==2) v += bv;
        Ob[(size_t)m*ldo + n] = v;
      }
    }
  }
}

// ---------------- depthwise 3x3 conv + bias + silu, vectorized d x4, register-sliding w ----------------
__global__ __launch_bounds__(256) void k_conv(const float* __restrict__ xd,
    const float* __restrict__ cw, const float* __restrict__ cb, float* __restrict__ u){
  const int z = blockIdx.y; const int g = z & 3;
  const int h = blockIdx.x;
  const int t = threadIdx.x;
  const int d4 = (t & 31) << 2;
  const int w0 = (t >> 5) << 3;
  float4 wv[9];
  #pragma unroll
  for (int q=0;q<9;q++){
    wv[q].x = cw[(g*DD + d4+0)*9 + q];
    wv[q].y = cw[(g*DD + d4+1)*9 + q];
    wv[q].z = cw[(g*DD + d4+2)*9 + q];
    wv[q].w = cw[(g*DD + d4+3)*9 + q];
  }
  float4 bs;
  bs.x = cb[g*DD+d4]; bs.y = cb[g*DD+d4+1]; bs.z = cb[g*DD+d4+2]; bs.w = cb[g*DD+d4+3];
  const float* xb = xd + (size_t)z*LDIM*DD;
  float* ub = u + (size_t)z*LDIM*DD;
  const bool hm = (h > 0), hp = (h < 63);
  const float4 Z = make_float4(0.f,0.f,0.f,0.f);

  float4 c0[3], c1[3], c2[3];
  #pragma unroll
  for (int r=0;r<3;r++){
    const int hh = h + r - 1;
    const bool rv = (r==0) ? hm : ((r==2) ? hp : true);
    c0[r] = (rv && w0 > 0) ? *(const float4*)&xb[(size_t)((hh<<6) + w0-1)*DD + d4] : Z;
    c1[r] = rv             ? *(const float4*)&xb[(size_t)((hh<<6) + w0  )*DD + d4] : Z;
  }

  #pragma unroll
  for (int ww=0; ww<8; ww++){
    const int wc = w0 + ww;
    #pragma unroll
    for (int r=0;r<3;r++){
      const int hh = h + r - 1;
      const bool rv = (r==0) ? hm : ((r==2) ? hp : true);
      c2[r] = (rv && wc < 63) ? *(const float4*)&xb[(size_t)((hh<<6) + wc+1)*DD + d4] : Z;
    }
    float4 a = bs;
    #pragma unroll
    for (int r=0;r<3;r++){
      a.x = fmaf(c0[r].x, wv[r*3+0].x, fmaf(c1[r].x, wv[r*3+1].x, fmaf(c2[r].x, wv[r*3+2].x, a.x)));
      a.y = fmaf(c0[r].y, wv[r*3+0].y, fmaf(c1[r].y, wv[r*3+1].y, fmaf(c2[r].y, wv[r*3+2].y, a.y)));
      a.z = fmaf(c0[r].z, wv[r*3+0].z, fmaf(c1[r].z, wv[r*3+1].z, fmaf(c2[r].z, wv[r*3+2].z, a.z)));
      a.w = fmaf(c0[r].w, wv[r*3+0].w, fmaf(c1[r].w, wv[r*3+1].w, fmaf(c2[r].w, wv[r*3+2].w, a.w)));
    }
    a.x = siluf(a.x); a.y = siluf(a.y); a.z = siluf(a.z); a.w = siluf(a.w);
    *(float4*)&ub[(size_t)((h<<6) + wc)*DD + d4] = a;
    #pragma unroll
    for (int r=0;r<3;r++){ c0[r] = c1[r]; c1[r] = c2[r]; }
  }
}

// scan-space -> memory-space index map
__device__ __forceinline__ int scan_lmem(int g0, int ls){
  int j = (g0 >= 2) ? (LDIM-1-ls) : ls;
  return (g0 & 1) ? (((j & 63)<<6) + (j >> 6)) : j;
}

__device__ __forceinline__ float softp(float xa){
  return (xa > 20.f) ? xa : __logf(1.f + __expf(xa));
}

// ---------------- scan phase A: 2 chunks per block (ILP=2), fast exp/log ----------------
__global__ __launch_bounds__(128) void k_scanA(const float* __restrict__ pd,
    const float* __restrict__ u, const float* __restrict__ dtb,
    const float* __restrict__ alog, float* __restrict__ P, float* __restrict__ Q){
  const int z = blockIdx.y; const int g = z & 3;
  const int ch0 = blockIdx.x*2, ch1 = ch0 + 1;
  const int d = threadIdx.x;
  const float bv = dtb[g*DD + d];
  const float Ad = -__expf(alog[g*DD + d]);
  const float* pdb = pd + (size_t)z*LDIM*132;
  const float* ubp = u + (size_t)z*LDIM*DD;
  float Pp0=1.f, q0=0.f, Pp1=1.f, q1=0.f;
  for (int i=0;i<CLEN;i++){
    const int lm0 = scan_lmem(g, ch0*CLEN + i);
    const int lm1 = scan_lmem(g, ch1*CLEN + i);
    const float* r0 = pdb + (size_t)lm0*132;
    const float* r1 = pdb + (size_t)lm1*132;
    float pre0 = r0[d],  pre1 = r1[d];
    float B0   = r0[128], B1  = r1[128];
    float u0 = ubp[(size_t)lm0*DD + d], u1 = ubp[(size_t)lm1*DD + d];
    float dl0 = softp(pre0 + bv), dl1 = softp(pre1 + bv);
    float dA0 = __expf(Ad*dl0),   dA1 = __expf(Ad*dl1);
    Pp0 *= dA0; Pp1 *= dA1;
    q0 = fmaf(dA0, q0, dl0*u0*B0);
    q1 = fmaf(dA1, q1, dl1*u1*B1);
  }
  const int i0 = (z*NCHUNK + ch0)*DD + d;
  const int i1 = (z*NCHUNK + ch1)*DD + d;
  P[i0]=Pp0; Q[i0]=q0; P[i1]=Pp1; Q[i1]=q1;
}

// ---------------- scan phase B ----------------
__global__ __launch_bounds__(128) void k_scanB(const float* __restrict__ P,
    const float* __restrict__ Q, float* __restrict__ hin){
  const int z = blockIdx.x; const int d = threadIdx.x;
  float h = 0.f;
  for (int j=0;j<NCHUNK;j++){
    const int idx = (z*NCHUNK + j)*DD + d;
    hin[idx] = h;
    h = fmaf(P[idx], h, Q[idx]);
  }
}

// ---------------- scan phase C: 2 chunks per block (ILP=2), fast exp/log ----------------
__global__ __launch_bounds__(128) void k_scanC(float* __restrict__ pd,
    const float* __restrict__ u, const float* __restrict__ dtb,
    const float* __restrict__ alog, const float* __restrict__ dsp,
    const float* __restrict__ hin){
  const int z = blockIdx.y; const int g = z & 3;
  const int ch0 = blockIdx.x*2, ch1 = ch0 + 1;
  const int d = threadIdx.x;
  const float bv = dtb[g*DD + d];
  const float Ad = -__expf(alog[g*DD + d]);
  const float Dv = dsp[g*DD + d];
  float* pdb = pd + (size_t)z*LDIM*132;
  const float* ubp = u + (size_t)z*LDIM*DD;
  float h0 = hin[(z*NCHUNK + ch0)*DD + d];
  float h1 = hin[(z*NCHUNK + ch1)*DD + d];
  for (int i=0;i<CLEN;i++){
    const int lm0 = scan_lmem(g, ch0*CLEN + i);
    const int lm1 = scan_lmem(g, ch1*CLEN + i);
    float* r0 = pdb + (size_t)lm0*132;
    float* r1 = pdb + (size_t)lm1*132;
    float pre0 = r0[d],  pre1 = r1[d];
    float B0 = r0[128], C0 = r0[129];
    float B1 = r1[128], C1 = r1[129];
    float u0 = ubp[(size_t)lm0*DD + d], u1 = ubp[(size_t)lm1*DD + d];
    float dl0 = softp(pre0 + bv), dl1 = softp(pre1 + bv);
    float dA0 = __expf(Ad*dl0),   dA1 = __expf(Ad*dl1);
    h0 = fmaf(dA0, h0, dl0*u0*B0);
    h1 = fmaf(dA1, h1, dl1*u1*B1);
    r0[d] = fmaf(h0, C0, Dv*u0);
    r1[d] = fmaf(h1, C1, Dv*u1);
  }
}

// ---------------- LN over D=128 per row (stride 132) * zsilu -> ynz (stride 128) ----------------
__global__ __launch_bounds__(256) void k_yln(const float* __restrict__ y,
    const float* __restrict__ zs, const float* __restrict__ og,
    const float* __restrict__ ob, float* __restrict__ ynz){
  const int row = blockIdx.x*4 + (threadIdx.x >> 6);
  const int lane = threadIdx.x & 63;
  const int g = (row >> 12) & 3;
  const float* r = y + (size_t)row*132;
  float v0 = r[lane], v1 = r[lane+64];
  float s = v0+v1, sq = fmaf(v0,v0, v1*v1);
  #pragma unroll
  for (int o=32;o;o>>=1){ s += __shfl_xor(s,o,64); sq += __shfl_xor(sq,o,64); }
  const float mu = s*(1.0f/DD);
  const float var = sq*(1.0f/DD) - mu*mu;
  const float rs = rsqrtf(var + 1e-5f);
  const size_t base = (size_t)row*DD;
  float o0 = (v0-mu)*rs*og[g*DD+lane]    + ob[g*DD+lane];
  float o1 = (v1-mu)*rs*og[g*DD+lane+64] + ob[g*DD+lane+64];
  ynz[base+lane]    = o0 * zs[base+lane];
  ynz[base+lane+64] = o1 * zs[base+lane+64];
}

// ---------------- final merge on (B,L,C): xm = ygrp*skip*xn*gate, LN over C, in-place. 1 wave/row ----
__global__ __launch_bounds__(256) void k_ln2r(float* __restrict__ yg,
    const float* __restrict__ xnT, const float* __restrict__ gate,
    const float* __restrict__ lg, const float* __restrict__ lb,
    const float* __restrict__ skp){
  const int row = blockIdx.x*4 + (threadIdx.x >> 6);   // (b,l) row, 0..32767
  const int b = row >> 12;
  const int lane = threadIdx.x & 63;
  const float sk = skp[0];
  float* yr = yg + (size_t)row*CC;
  const float* xr = xnT + (size_t)row*CC;
  const float* gb = gate + b*CC;
  float v[8]; float s=0.f, sq=0.f;
  #pragma unroll
  for (int i=0;i<8;i++){
    const int c = lane + 64*i;
    float val = yr[c] * sk * xr[c] * gb[c];
    v[i] = val; s += val; sq = fmaf(val,val,sq);
  }
  #pragma unroll
  for (int o=32;o;o>>=1){ s += __shfl_xor(s,o,64); sq += __shfl_xor(sq,o,64); }
  const float mu = s*(1.0f/CC);
  const float var = sq*(1.0f/CC) - mu*mu;
  const float rs = rsqrtf(var + 1e-5f);
  #pragma unroll
  for (int i=0;i<8;i++){
    const int c = lane + 64*i;
    yr[c] = (v[i]-mu)*rs*lg[c] + lb[c];
  }
}

extern "C" void kernel_launch(void* const* d_in, const int* in_sizes, int n_in,
                              void* d_out, int out_size, void* d_ws, size_t ws_size,
                              hipStream_t stream) {
  const float* x    = (const float*)d_in[0];
  const float* ln_g = (const float*)d_in[1];
  const float* ln_b = (const float*)d_in[2];
  const float* f1w  = (const float*)d_in[3];
  const float* f1b  = (const float*)d_in[4];
  const float* f2w  = (const float*)d_in[5];
  const float* f2b  = (const float*)d_in[6];
  const float* ipw  = (const float*)d_in[7];
  const float* cw   = (const float*)d_in[8];
  const float* cb   = (const float*)d_in[9];
  const float* xpw  = (const float*)d_in[10];
  const float* dtpw = (const float*)d_in[11];
  const float* dtpb = (const float*)d_in[12];
  const float* alog = (const float*)d_in[13];
  const float* dsp  = (const float*)d_in[14];
  const float* ong  = (const float*)d_in[15];
  const float* onb  = (const float*)d_in[16];
  const float* opw  = (const float*)d_in[17];
  const float* pjw  = (const float*)d_in[18];
  const float* pjb  = (const float*)d_in[19];
  const float* skp  = (const float*)d_in[20];

  float* ws   = (float*)d_ws;
  float* xn   = ws;                       // (B,L,C) fused LN+transpose output
  float* ub   = ws + 16777216;            // (B*G,L,128) u / later ynz
  float* pd   = ws + 33554432;            // (B*G,L,132) pd/y -> (B,L,C) ygrp/xmn
  float* zsum = ws + 50855936;            // 4096
  float* gate = ws + 50860032;            // 4096
  float* w2   = ws + 50864128;            // 4*132*128
  float* xdz  = (float*)d_out;            // xd -> P/Q/hin scan scratch -> zsilu
  float* Pb   = xdz;                      // 262144 (NCHUNK=64)
  float* Qb   = xdz + 262144;             // 262144
  float* hin  = xdz + 524288;             // 262144

  const long long LC  = (long long)LDIM*CC;     // 2M
  const long long LD  = (long long)LDIM*DD;     // 512K
  const long long LPD = (long long)LDIM*132;

  hipMemsetAsync(zsum, 0, 4096*sizeof(float), stream);

  // fused LN over C + transpose -> xn (B,L,C), + gate channel sums
  k_ln1t<<<dim3(64, BB), 256, 0, stream>>>(x, ln_g, ln_b, xn, zsum);
  k_gate<<<BB, 256, 0, stream>>>(zsum, f1w, f1b, f2w, f2b, gate);
  k_wm<<<GG, 128, 0, stream>>>(xpw, dtpw, w2);

  // G1a: xd[z][l][d] = xn[b][l][g*128+k] @ ipw[g][0:128]
  k_mfma<4,0,false><<<dim3(32,1,32), 256, 0, stream>>>(
      xn, LC, 128, CC, ipw, 0, 2*DD*DD, xdz, 4*LD, LD, DD, DD, DD, nullptr);

  k_conv<<<dim3(64,32), 256, 0, stream>>>(xdz, cw, cb, ub);

  // G2: pd[z][l][0:130] = u @ W2^T (NF=5 tile, cols>=130 guarded)
  k_mfma<5,0,true><<<dim3(32,1,32), 256, 0, stream>>>(
      ub, 4*LD, LD, DD, w2, 0, 132*DD, pd, 4*LPD, LPD, 132, DD, 130, nullptr);

  // chunked selective scan (P/Q/hin live in d_out scratch; xd already consumed)
  k_scanA<<<dim3(NCHUNK/2,32), 128, 0, stream>>>(pd, ub, dtpb, alog, Pb, Qb);
  k_scanB<<<32, 128, 0, stream>>>(Pb, Qb, hin);
  k_scanC<<<dim3(NCHUNK/2,32), 128, 0, stream>>>(pd, ub, dtpb, alog, dsp, hin);

  // G1b: zsilu = silu(xn @ ipw[g][128:256]) -> xdz
  k_mfma<4,1,false><<<dim3(32,1,32), 256, 0, stream>>>(
      xn, LC, 128, CC, ipw + DD*DD, 0, 2*DD*DD, xdz, 4*LD, LD, DD, DD, DD, nullptr);

  // LN over D * zsilu -> ynz (into ub)
  k_yln<<<32768, 256, 0, stream>>>(pd, xdz, ong, onb, ub);

  // G3: ygrp[b][l][g*128+n] = ynz @ opw[g]^T  (into pd as (B,L,C))
  k_mfma<4,0,false><<<dim3(32,1,32), 256, 0, stream>>>(
      ub, 4*LD, LD, DD, opw, 0, DD*DD, pd, LC, 128, CC, DD, DD, nullptr);

  // merge + LN over C, in-place on pd (B,L,C)
  k_ln2r<<<8192, 256, 0, stream>>>(pd, xn, gate, ln_g, ln_b, skp);

  // G4: out[b][c][l] = proj_w[c,:] . xmn[b][l][:] + pjb[c]  (A=pjw M=512, B=xmn N=4096)
  k_mfma<4,2,false><<<dim3(4,32,BB), 256, 0, stream>>>(
      pjw, 0, 0, CC, pd, 4*LC, LC, (float*)d_out, 4*(long long)CC*LDIM, (long long)CC*LDIM, LDIM, CC, LDIM, pjb);

  (void)in_sizes; (void)n_in; (void)out_size; (void)ws_size;
}